// Round 18
// baseline (1067.079 us; speedup 1.0000x reference)
//
#include <hip/hip_runtime.h>
#include <hip/hip_bf16.h>
#include <math.h>

#define BATCH 8
#define NPTS  2048
#define KNN   20
#define NEG_INF (-3.402823466e38f)

static __device__ __forceinline__ float bn_scale(float g){ return g * rsqrtf(1.0f + 1e-5f); }

// bf16 round-to-nearest-even
static __device__ __forceinline__ unsigned short bf16r(float f){
  unsigned int u = __float_as_uint(f);
  unsigned int r = (u + 0x7fffu + ((u >> 16) & 1u)) >> 16;
  return (unsigned short)r;
}
static __device__ __forceinline__ float bf2f(unsigned short h){
  return __uint_as_float((unsigned int)h << 16);
}
// ordered-int encode/decode for float max via atomicMax(uint)
static __device__ __forceinline__ unsigned int fenc(float f){
  unsigned int u = __float_as_uint(f);
  return (u & 0x80000000u) ? ~u : (u | 0x80000000u);
}
static __device__ __forceinline__ float fdec(unsigned int e){
  return __uint_as_float((e & 0x80000000u) ? (e & 0x7fffffffu) : ~e);
}

using bfrag = __attribute__((ext_vector_type(8))) short;  // 8 bf16 (4 VGPRs)
using f32x4 = __attribute__((ext_vector_type(4))) float;  // 4 fp32 acc
using f32x2 = __attribute__((ext_vector_type(2))) float;

// ---- DPP-based wave argmax (lexicographic value desc, idx asc); winner in lane 63 ----
template<int CTRL>
static __device__ __forceinline__ void dpp_amax(float &bv, int &bi){
  int ov_i = __builtin_amdgcn_update_dpp(__float_as_int(NEG_INF), __float_as_int(bv),
                                         CTRL, 0xf, 0xf, false);
  int oi   = __builtin_amdgcn_update_dpp(0x7fffffff, bi, CTRL, 0xf, 0xf, false);
  float ov = __int_as_float(ov_i);
  if (ov > bv || (ov == bv && oi < bi)){ bv = ov; bi = oi; }
}
static __device__ __forceinline__ int wave_argmax_idx(float bv, int bi){
  dpp_amax<0x111>(bv, bi);   // row_shr:1
  dpp_amax<0x112>(bv, bi);   // row_shr:2
  dpp_amax<0x114>(bv, bi);   // row_shr:4
  dpp_amax<0x118>(bv, bi);   // row_shr:8
  dpp_amax<0x142>(bv, bi);   // row_bcast:15
  dpp_amax<0x143>(bv, bi);   // row_bcast:31
  return __builtin_amdgcn_readlane(bi, 63);
}
// ---- DPP wave sum (identity 0.0 injected); total broadcast from lane 63 ----
template<int CTRL>
static __device__ __forceinline__ float dpp_fadd(float v){
  int ov = __builtin_amdgcn_update_dpp(0, __float_as_int(v), CTRL, 0xf, 0xf, false);
  return v + __int_as_float(ov);
}
static __device__ __forceinline__ float wave_sum(float v){
  v = dpp_fadd<0x111>(v); v = dpp_fadd<0x112>(v);
  v = dpp_fadd<0x114>(v); v = dpp_fadd<0x118>(v);
  v = dpp_fadd<0x142>(v); v = dpp_fadd<0x143>(v);
  return __int_as_float(__builtin_amdgcn_readlane(__float_as_int(v), 63));
}
// ---- sorted top-4 insertion (value desc, idx asc; strict > keeps smallest idx) ----
static __device__ __forceinline__ void ins4(float v, int m,
    float&s0,float&s1,float&s2,float&s3,int&i0,int&i1,int&i2,int&i3){
  const bool b0 = v > s0, b1 = v > s1, b2 = v > s2, b3 = v > s3;
  const float n0 = b0 ? v : s0;             const int q0 = b0 ? m : i0;
  const float n1 = b0 ? s0 : (b1 ? v : s1); const int q1 = b0 ? i0 : (b1 ? m : i1);
  const float n2 = b1 ? s1 : (b2 ? v : s2); const int q2 = b1 ? i1 : (b2 ? m : i2);
  const float n3 = b2 ? s2 : (b3 ? v : s3); const int q3 = b2 ? i2 : (b3 ? m : i3);
  s0=n0;s1=n1;s2=n2;s3=n3; i0=q0;i1=q1;i2=q2;i3=q3;
}

// ---------------- squared norms, channel-major (layer 1, C=3) ----------------
__global__ void sqnorm_kernel(const float* __restrict__ X, float* __restrict__ sq, int C){
  int i = blockIdx.x*blockDim.x + threadIdx.x;
  if (i >= BATCH*NPTS) return;
  int b = i / NPTS, n = i - b*NPTS;
  const float* xb = X + (size_t)b*C*NPTS + n;
  float s = 0.f;
  for (int c=0;c<C;++c){ float v = xb[(size_t)c*NPTS]; s += v*v; }
  sq[i] = s;
}

// ---------------- squared norms, point-major (layers 2-4); ascending-c order ----------
__global__ void sqnorm_pm_kernel(const float* __restrict__ xT, float* __restrict__ sq, int C){
  int i = blockIdx.x*blockDim.x + threadIdx.x;
  if (i >= BATCH*NPTS) return;
  const float* r = xT + (size_t)i*C;
  float s = 0.f;
  for (int c4=0; c4<C; c4+=4){
    float4 v = *(const float4*)&r[c4];
    s += v.x*v.x; s += v.y*v.y; s += v.z*v.z; s += v.w*v.w;
  }
  sq[i] = s;
}

// ---------------- kNN layer 1 only (C=3): LDS dist + top-4 queue + DPP argmax ----------
template<int C>
__global__ __launch_bounds__(256, 2) void knn_kernel(const float* __restrict__ X,
                                                     const float* __restrict__ sq,
                                                     int* __restrict__ idxout){
  const int b = blockIdx.y;
  const int n0 = blockIdx.x * 8;
  const int t = threadIdx.x;
  __shared__ __align__(16) float dist[4][NPTS];
  __shared__ float ctrs[C][8];
  __shared__ float sqn[8];
  const float* xb = X + (size_t)b*C*NPTS;
  for (int i=t; i<C*8; i+=256){
    int c = i >> 3, p = i & 7;
    ctrs[c][p] = xb[(size_t)c*NPTS + n0 + p];
  }
  if (t < 8) sqn[t] = sq[b*NPTS + n0 + t];
  __syncthreads();

  const int m0 = t * 8;
  float acc[8][8];
  #pragma unroll
  for (int i=0;i<8;++i)
    #pragma unroll
    for (int j=0;j<8;++j) acc[i][j] = 0.f;
  for (int c=0;c<C;++c){
    const float4 xa = *(const float4*)&xb[(size_t)c*NPTS + m0];
    const float4 xc = *(const float4*)&xb[(size_t)c*NPTS + m0 + 4];
    const float xm[8] = {xa.x,xa.y,xa.z,xa.w,xc.x,xc.y,xc.z,xc.w};
    #pragma unroll
    for (int i=0;i<8;++i){
      const float cv = ctrs[c][i];
      #pragma unroll
      for (int j=0;j<8;++j) acc[i][j] += cv*xm[j];
    }
  }
  {
    const float4 sa = *(const float4*)&sq[b*NPTS + m0];
    const float4 sb = *(const float4*)&sq[b*NPTS + m0 + 4];
    const float sm[8] = {sa.x,sa.y,sa.z,sa.w,sb.x,sb.y,sb.z,sb.w};
    #pragma unroll
    for (int i=0;i<8;++i){
      const float si = sqn[i];
      #pragma unroll
      for (int j=0;j<8;++j) acc[i][j] = 2.f*acc[i][j] - si - sm[j];
    }
  }

  const int wv = t >> 6, lane = t & 63;
  #pragma unroll
  for (int rep=0; rep<2; ++rep){
    #pragma unroll
    for (int i=0;i<4;++i){
      *(float4*)&dist[i][m0]   = make_float4(acc[rep*4+i][0],acc[rep*4+i][1],acc[rep*4+i][2],acc[rep*4+i][3]);
      *(float4*)&dist[i][m0+4] = make_float4(acc[rep*4+i][4],acc[rep*4+i][5],acc[rep*4+i][6],acc[rep*4+i][7]);
    }
    __syncthreads();
    float s0=NEG_INF,s1=NEG_INF,s2=NEG_INF,s3=NEG_INF;
    int   i0=0x7fffffff,i1=0x7fffffff,i2=0x7fffffff,i3=0x7fffffff;
    #pragma unroll
    for (int j=0;j<32;++j){
      const float v = dist[wv][lane + 64*j];
      ins4(v, lane + 64*j, s0,s1,s2,s3, i0,i1,i2,i3);
    }
    int rem = 4;
    int* row = idxout + ((size_t)b*NPTS + n0 + rep*4 + wv)*KNN;
    for (int sel=0; sel<KNN; ++sel){
      const int widx = wave_argmax_idx(s0, i0);
      if (lane == 0) row[sel] = widx;
      if ((widx & 63) == lane){
        const float lastv = s0; const int lasti = i0;
        s0=s1;i0=i1; s1=s2;i1=i2; s2=s3;i2=i3;
        rem--;
        if (rem == 0){
          float nv = NEG_INF; int ni = 0x7fffffff;
          #pragma unroll
          for (int j=0;j<32;++j){
            const float vv = dist[wv][lane + 64*j];
            const int   mi = lane + 64*j;
            const bool ok = (vv < lastv) || (vv == lastv && mi > lasti);
            if (ok && vv > nv){ nv = vv; ni = mi; }
          }
          s0 = nv; i0 = ni; rem = 1;
        }
      }
    }
    __syncthreads();
  }
}

// ---------------- dist GEMM (layers 2-4): D[n][m] = 2*x_n.x_m - sqn - sqm ---------------
// conv5_v3-style LDS-staged split-bf16 MFMA (r10 numerics: hh, hl, lh accumulation).
// xh/xl are pre-offset to (batch row base + column base); row stride 512 shorts.
template<int CK>
__global__ __launch_bounds__(256) void distgemm(const unsigned short* __restrict__ xh,
    const unsigned short* __restrict__ xl, const float* __restrict__ sqb,
    float* __restrict__ D){
  constexpr int KSTEPS = CK/32;
  __shared__ __align__(16) unsigned short Ah_s[128*32];
  __shared__ __align__(16) unsigned short Al_s[128*32];
  __shared__ __align__(16) unsigned short Bh_s[64*32];
  __shared__ __align__(16) unsigned short Bl_s[64*32];
  const int t = threadIdx.x;
  const int n0 = blockIdx.x*128, m0 = blockIdx.y*64;
  const int wv = t >> 6, l = t & 63, lane15 = l & 15, quad = l >> 4;
  const int ar = t >> 2, ac = (t & 3)*8;
  f32x4 acc[2][4];
  #pragma unroll
  for (int mt=0;mt<2;++mt)
    #pragma unroll
    for (int nt=0;nt<4;++nt) acc[mt][nt] = (f32x4){0.f,0.f,0.f,0.f};

  for (int ks=0; ks<KSTEPS; ++ks){
    const int ko = ks*32 + ac;
    uint4 a0 = *(const uint4*)&xh[(size_t)(n0 + ar)*512 + ko];
    uint4 a1 = *(const uint4*)&xh[(size_t)(n0 + 64 + ar)*512 + ko];
    uint4 a2 = *(const uint4*)&xl[(size_t)(n0 + ar)*512 + ko];
    uint4 a3 = *(const uint4*)&xl[(size_t)(n0 + 64 + ar)*512 + ko];
    uint4 bh = *(const uint4*)&xh[(size_t)(m0 + ar)*512 + ko];
    uint4 bl = *(const uint4*)&xl[(size_t)(m0 + ar)*512 + ko];
    *(uint4*)&Ah_s[t*8]        = a0;
    *(uint4*)&Ah_s[2048 + t*8] = a1;
    *(uint4*)&Al_s[t*8]        = a2;
    *(uint4*)&Al_s[2048 + t*8] = a3;
    *(uint4*)&Bh_s[t*8]        = bh;
    *(uint4*)&Bl_s[t*8]        = bl;
    __syncthreads();
    bfrag Afh[2], Afl[2], Bfh[4], Bfl[4];
    #pragma unroll
    for (int mt=0;mt<2;++mt){
      const int r = wv*32 + mt*16 + lane15;
      Afh[mt] = *(const bfrag*)&Ah_s[r*32 + quad*8];
      Afl[mt] = *(const bfrag*)&Al_s[r*32 + quad*8];
    }
    #pragma unroll
    for (int nt=0;nt<4;++nt){
      const int c = nt*16 + lane15;
      Bfh[nt] = *(const bfrag*)&Bh_s[c*32 + quad*8];
      Bfl[nt] = *(const bfrag*)&Bl_s[c*32 + quad*8];
    }
    #pragma unroll
    for (int mt=0;mt<2;++mt)
      #pragma unroll
      for (int nt=0;nt<4;++nt){
        acc[mt][nt] = __builtin_amdgcn_mfma_f32_16x16x32_bf16(Afh[mt], Bfh[nt], acc[mt][nt], 0, 0, 0);
        acc[mt][nt] = __builtin_amdgcn_mfma_f32_16x16x32_bf16(Afh[mt], Bfl[nt], acc[mt][nt], 0, 0, 0);
        acc[mt][nt] = __builtin_amdgcn_mfma_f32_16x16x32_bf16(Afl[mt], Bfh[nt], acc[mt][nt], 0, 0, 0);
      }
    __syncthreads();
  }
  // epilogue: D[n][m] = 2*acc - sq[n] - sq[m]
  float sqn_r[2][4];
  #pragma unroll
  for (int mt=0;mt<2;++mt)
    #pragma unroll
    for (int r=0;r<4;++r) sqn_r[mt][r] = sqb[n0 + wv*32 + mt*16 + quad*4 + r];
  #pragma unroll
  for (int nt=0;nt<4;++nt){
    const int m = m0 + nt*16 + lane15;
    const float sqm = sqb[m];
    #pragma unroll
    for (int mt=0;mt<2;++mt)
      #pragma unroll
      for (int r=0;r<4;++r){
        const int n = n0 + wv*32 + mt*16 + quad*4 + r;
        D[(size_t)n*NPTS + m] = 2.f*acc[mt][nt][r] - sqn_r[mt][r] - sqm;
      }
  }
}

// ---------------- kNN select (layers 2-4): wave per point over global D row -------------
// lane owns m = (lane + 64j)*4 + e (j<8, e<4): coalesced float4 reads, m ascending within
// lane; top-4 queue + DPP argmax; refill re-reads (L2-hot). Bit-exact lax.top_k ties.
__global__ __launch_bounds__(256) void knn_select(const float* __restrict__ D,
                                                  int* __restrict__ idxb){
  const int p = blockIdx.x*4 + (threadIdx.x >> 6);
  const int lane = threadIdx.x & 63;
  const float4* row4 = (const float4*)(D + (size_t)p*NPTS);
  float s0=NEG_INF,s1=NEG_INF,s2=NEG_INF,s3=NEG_INF;
  int   i0=0x7fffffff,i1=0x7fffffff,i2=0x7fffffff,i3=0x7fffffff;
  #pragma unroll
  for (int j=0;j<8;++j){
    const float4 v4 = row4[lane + 64*j];
    const int mb = (lane + 64*j)*4;
    ins4(v4.x, mb+0, s0,s1,s2,s3, i0,i1,i2,i3);
    ins4(v4.y, mb+1, s0,s1,s2,s3, i0,i1,i2,i3);
    ins4(v4.z, mb+2, s0,s1,s2,s3, i0,i1,i2,i3);
    ins4(v4.w, mb+3, s0,s1,s2,s3, i0,i1,i2,i3);
  }
  int rem = 4;
  int* out = idxb + p*KNN;
  for (int sel=0; sel<KNN; ++sel){
    const int widx = wave_argmax_idx(s0, i0);
    if (lane == 0) out[sel] = widx;
    if (((widx >> 2) & 63) == lane){
      const float lastv = s0; const int lasti = i0;
      s0=s1;i0=i1; s1=s2;i1=i2; s2=s3;i2=i3;
      rem--;
      if (rem == 0){
        float nv = NEG_INF; int ni = 0x7fffffff;
        #pragma unroll
        for (int j=0;j<8;++j){
          const float4 v4 = row4[lane + 64*j];
          const int mb = (lane + 64*j)*4;
          const float va[4] = {v4.x, v4.y, v4.z, v4.w};
          #pragma unroll
          for (int e=0;e<4;++e){
            const float vv = va[e]; const int mi = mb + e;
            const bool ok = (vv < lastv) || (vv == lastv && mi > lasti);
            if (ok && vv > nv){ nv = vv; ni = mi; }
          }
        }
        s0 = nv; i0 = ni; rem = 1;
      }
    }
  }
}

// ---------------- fp32 weight prep (layer 1 only): wnT[c][o], wdT[c][o] ----------------
__global__ void wprep_kernel(const float* __restrict__ w, float* __restrict__ wnT,
                             float* __restrict__ wdT, int O, int C){
  int i = blockIdx.x*blockDim.x + threadIdx.x;
  if (i >= O*C) return;
  int c = i / O, o = i - c*O;
  float a = w[(size_t)o*2*C + c];
  wnT[(size_t)c*O + o] = a;
  wdT[(size_t)c*O + o] = w[(size_t)o*2*C + C + c] - a;
}

// ---------------- bf16 weight prep (layers 2-4): wn[o][c], wd[o][c] (k contiguous) -----
__global__ void wprep_bf_kernel(const float* __restrict__ w, unsigned short* __restrict__ wn,
                                unsigned short* __restrict__ wd, int O, int C){
  int i = blockIdx.x*blockDim.x + threadIdx.x;
  if (i >= O*C) return;
  int o = i / C, c = i - o*C;
  float a = w[(size_t)o*2*C + c];
  float d = w[(size_t)o*2*C + C + c] - a;
  wn[(size_t)o*C + c] = bf16r(a);
  wd[(size_t)o*C + c] = bf16r(d);
}

// ---------------- split-bf16 weight convert (conv5): hi = bf16(w), lo = bf16(w-hi) ------
__global__ void bfsplit_kernel(const float* __restrict__ in, unsigned short* __restrict__ hi,
                               unsigned short* __restrict__ lo, int nq){
  int i = blockIdx.x*blockDim.x + threadIdx.x;
  if (i >= nq) return;
  float4 v = *(const float4*)&in[(size_t)i*4];
  unsigned short h0=bf16r(v.x), h1=bf16r(v.y), h2=bf16r(v.z), h3=bf16r(v.w);
  unsigned short l0=bf16r(v.x-bf2f(h0)), l1=bf16r(v.y-bf2f(h1)),
                 l2=bf16r(v.z-bf2f(h2)), l3=bf16r(v.w-bf2f(h3));
  *(uint2*)&hi[(size_t)i*4] = make_uint2((unsigned)h0|((unsigned)h1<<16), (unsigned)h2|((unsigned)h3<<16));
  *(uint2*)&lo[(size_t)i*4] = make_uint2((unsigned)l0|((unsigned)l1<<16), (unsigned)l2|((unsigned)l3<<16));
}

// ---------------- xsplit: fp32 [b][n][Csrc] -> split-bf16 xcat slice (stride 512) -------
__global__ __launch_bounds__(256) void xsplit_kernel(const float* __restrict__ src,
    unsigned short* __restrict__ hi, unsigned short* __restrict__ lo, int Cq){ // Cq = Csrc/4
  int i = blockIdx.x*blockDim.x + threadIdx.x;
  if (i >= BATCH*NPTS*Cq) return;
  int bn_ = i / Cq, q = i - bn_*Cq;
  float4 v = *(const float4*)&src[(size_t)i*4];
  unsigned short h0=bf16r(v.x), h1=bf16r(v.y), h2=bf16r(v.z), h3=bf16r(v.w);
  unsigned short l0=bf16r(v.x-bf2f(h0)), l1=bf16r(v.y-bf2f(h1)),
                 l2=bf16r(v.z-bf2f(h2)), l3=bf16r(v.w-bf2f(h3));
  const size_t d = (size_t)bn_*512 + q*4;
  *(uint2*)&hi[d] = make_uint2((unsigned)h0|((unsigned)h1<<16), (unsigned)h2|((unsigned)h3<<16));
  *(uint2*)&lo[d] = make_uint2((unsigned)l0|((unsigned)l1<<16), (unsigned)l2|((unsigned)l3<<16));
}

// ---------------- x -> xT0 [N][3] ----------------
__global__ void xt0_kernel(const float* __restrict__ x, float* __restrict__ xT0){
  int i = blockIdx.x*blockDim.x + threadIdx.x;
  if (i >= BATCH*NPTS) return;
  int b = i / NPTS, n = i - b*NPTS;
  const float* xb = x + (size_t)b*3*NPTS;
  float v0 = xb[n], v1 = xb[NPTS + n], v2 = xb[2*NPTS + n];
  float* o = xT0 + ((size_t)b*NPTS + n)*3;
  o[0]=v0; o[1]=v1; o[2]=v2;
}

// ---------------- edge conv layer 1 (C=3, fp32): 4 points per block ----------------
__global__ __launch_bounds__(256) void edgeconv1_kernel(const float* __restrict__ xT0,
    const int* __restrict__ idx, const float* __restrict__ wnT, const float* __restrict__ wdT,
    const float* __restrict__ g, const float* __restrict__ bb, float* __restrict__ outT){
  const int b = blockIdx.y, n0 = blockIdx.x*4, t = threadIdx.x;
  __shared__ float nbr[4][KNN][3];
  __shared__ float ctr[4][3];
  __shared__ int   idxs[4][KNN];
  const float* xb = xT0 + (size_t)b*NPTS*3;
  if (t < 4*KNN) idxs[t/KNN][t%KNN] = idx[((size_t)b*NPTS + n0 + t/KNN)*KNN + (t%KNN)];
  if (t >= 128 && t < 140){ int i = t-128; ctr[i/3][i%3] = xb[(size_t)(n0 + i/3)*3 + i%3]; }
  __syncthreads();
  for (int i=t; i<4*KNN*3; i+=256){
    int p = i/(KNN*3), r = i - p*(KNN*3), k = r/3, c = r - k*3;
    nbr[p][k][c] = xb[(size_t)idxs[p][k]*3 + c];
  }
  __syncthreads();
  const int p = t >> 6, o = t & 63;
  const float wn0 = wnT[o], wn1 = wnT[64+o], wn2 = wnT[128+o];
  const float cst = ctr[p][0]*wdT[o] + ctr[p][1]*wdT[64+o] + ctr[p][2]*wdT[128+o];
  float best = NEG_INF;
  #pragma unroll
  for (int k=0;k<KNN;++k){
    float a = nbr[p][k][0]*wn0 + nbr[p][k][1]*wn1 + nbr[p][k][2]*wn2;
    best = fmaxf(best, a);
  }
  float vv = (best + cst) * bn_scale(g[o]) + bb[o];
  outT[((size_t)b*NPTS + n0 + p)*64 + o] = fmaxf(vv, 0.f);
}

// ---------------- edge conv MFMA (bf16): block = 4 points ----------------
template<int C, int O>
__global__ __launch_bounds__(256) void edgeconv_mfma(const float* __restrict__ xT,
    const int* __restrict__ idx,
    const unsigned short* __restrict__ wn_bf, const unsigned short* __restrict__ wd_bf,
    const float* __restrict__ g, const float* __restrict__ bb, float* __restrict__ outT){
  constexpr int ROWS = 112;        // 7 m-tiles of 16
  constexpr int CP   = C + 8;      // padded row (bf16): 16B-aligned stride, conflict-free b128
  constexpr int KS   = C / 32;     // k-steps per tile
  constexpr int NTW  = O / 64;     // n-tiles per wave (O/16 tiles over 4 waves)
  __shared__ __align__(16) unsigned short A[ROWS][CP];
  __shared__ unsigned int res[4][O];
  __shared__ float cst_s[4][O];
  __shared__ int idxs[4][KNN];
  const int b = blockIdx.y, n0 = blockIdx.x*4, t = threadIdx.x;
  const float* xTb = xT + (size_t)b*NPTS*C;
  if (t < 4*KNN) idxs[t/KNN][t%KNN] = idx[((size_t)b*NPTS + n0 + t/KNN)*KNN + (t%KNN)];
  for (int i=t; i<4*O; i+=256) res[i/O][i & (O-1)] = 0u;   // 0 < fenc(any finite)
  __syncthreads();
  for (int i=t; i<ROWS*(C/4); i+=256){
    int r = i/(C/4), c4 = i - r*(C/4);
    float4 v = make_float4(0.f,0.f,0.f,0.f);
    if (r < 96){
      int p = r/24, kk = r - p*24;
      int src = idxs[p][kk < KNN ? kk : 0];        // pad rows duplicate nbr 0 (max-neutral)
      v = *(const float4*)&xTb[(size_t)src*C + c4*4];
    } else if (r < 100){
      v = *(const float4*)&xTb[(size_t)(n0 + (r-96))*C + c4*4];
    }
    unsigned int lo = (unsigned int)bf16r(v.x) | ((unsigned int)bf16r(v.y) << 16);
    unsigned int hi = (unsigned int)bf16r(v.z) | ((unsigned int)bf16r(v.w) << 16);
    *(uint2*)&A[r][c4*4] = make_uint2(lo, hi);
  }
  __syncthreads();

  const int wv = t >> 6, l = t & 63;
  const int lane15 = l & 15, quad = l >> 4;
  bfrag Bn[NTW][KS];
  #pragma unroll
  for (int nt=0; nt<NTW; ++nt){
    const int col = (wv*NTW + nt)*16 + lane15;
    #pragma unroll
    for (int s=0; s<KS; ++s)
      Bn[nt][s] = *(const bfrag*)&wn_bf[(size_t)col*C + s*32 + quad*8];
  }
  #pragma unroll
  for (int mt=0; mt<7; ++mt){
    bfrag Af[KS];
    #pragma unroll
    for (int s=0; s<KS; ++s)
      Af[s] = *(const bfrag*)&A[mt*16 + lane15][s*32 + quad*8];
    if (mt < 6){
      const int rbase = mt*16 + quad*4;
      const int p = rbase / 24;
      #pragma unroll
      for (int nt=0; nt<NTW; ++nt){
        f32x4 acc = {0.f,0.f,0.f,0.f};
        #pragma unroll
        for (int s=0; s<KS; ++s)
          acc = __builtin_amdgcn_mfma_f32_16x16x32_bf16(Af[s], Bn[nt][s], acc, 0, 0, 0);
        float m = fmaxf(fmaxf(acc[0], acc[1]), fmaxf(acc[2], acc[3]));
        const int col = (wv*NTW + nt)*16 + lane15;
        atomicMax(&res[p][col], fenc(m));
      }
    } else {
      #pragma unroll
      for (int nt=0; nt<NTW; ++nt){
        const int col = (wv*NTW + nt)*16 + lane15;
        f32x4 acc = {0.f,0.f,0.f,0.f};
        #pragma unroll
        for (int s=0; s<KS; ++s){
          bfrag Bd = *(const bfrag*)&wd_bf[(size_t)col*C + s*32 + quad*8];
          acc = __builtin_amdgcn_mfma_f32_16x16x32_bf16(Af[s], Bd, acc, 0, 0, 0);
        }
        if (quad == 0){
          #pragma unroll
          for (int r=0;r<4;++r) cst_s[r][col] = acc[r];
        }
      }
    }
  }
  __syncthreads();
  for (int i=t; i<4*O; i+=256){
    int p = i/O, o = i - p*O;
    float mx = fdec(res[p][o]);
    float vv = (mx + cst_s[p][o]) * bn_scale(g[o]) + bb[o];
    outT[((size_t)b*NPTS + n0 + p)*O + o] = fmaxf(vv, 0.f);
  }
}

// ---------------- conv5 v3: LDS-staged split-bf16 MFMA GEMM + max over n ----------------
__global__ __launch_bounds__(256) void conv5_v3(const unsigned short* __restrict__ xhi,
    const unsigned short* __restrict__ xlo, const unsigned short* __restrict__ whi,
    const unsigned short* __restrict__ wlo, const float* __restrict__ g,
    const float* __restrict__ bb, float* __restrict__ out5){
  __shared__ __align__(16) unsigned short Ah_s[128*32];
  __shared__ __align__(16) unsigned short Al_s[128*32];
  __shared__ __align__(16) unsigned short Bh_s[64*32];
  __shared__ __align__(16) unsigned short Bl_s[64*32];
  const int t = threadIdx.x;
  const int row0 = blockIdx.x*128, o0 = blockIdx.y*64;
  const int b = row0 / NPTS;   // 128 | NPTS, so a block never straddles batches
  const int wv = t >> 6, l = t & 63, lane15 = l & 15, quad = l >> 4;
  const int ar = t >> 2, ac = (t & 3)*8;
  const unsigned short* gAh0 = xhi + (size_t)(row0 + ar)*512 + ac;
  const unsigned short* gAh1 = xhi + (size_t)(row0 + 64 + ar)*512 + ac;
  const unsigned short* gAl0 = xlo + (size_t)(row0 + ar)*512 + ac;
  const unsigned short* gAl1 = xlo + (size_t)(row0 + 64 + ar)*512 + ac;
  const unsigned short* gBh  = whi + (size_t)(o0 + ar)*512 + ac;
  const unsigned short* gBl  = wlo + (size_t)(o0 + ar)*512 + ac;

  uint4 pf0 = *(const uint4*)gAh0;
  uint4 pf1 = *(const uint4*)gAh1;
  uint4 pf2 = *(const uint4*)gAl0;
  uint4 pf3 = *(const uint4*)gAl1;
  uint4 pf4 = *(const uint4*)gBh;
  uint4 pf5 = *(const uint4*)gBl;

  f32x4 acc[2][4];
  #pragma unroll
  for (int mt=0;mt<2;++mt)
    #pragma unroll
    for (int nt=0;nt<4;++nt) acc[mt][nt] = (f32x4){0.f,0.f,0.f,0.f};

  for (int ks=0; ks<16; ++ks){
    *(uint4*)&Ah_s[t*8]        = pf0;
    *(uint4*)&Ah_s[2048 + t*8] = pf1;
    *(uint4*)&Al_s[t*8]        = pf2;
    *(uint4*)&Al_s[2048 + t*8] = pf3;
    *(uint4*)&Bh_s[t*8]        = pf4;
    *(uint4*)&Bl_s[t*8]        = pf5;
    __syncthreads();
    if (ks < 15){
      const int koff = (ks+1)*32;
      pf0 = *(const uint4*)(gAh0 + koff);
      pf1 = *(const uint4*)(gAh1 + koff);
      pf2 = *(const uint4*)(gAl0 + koff);
      pf3 = *(const uint4*)(gAl1 + koff);
      pf4 = *(const uint4*)(gBh  + koff);
      pf5 = *(const uint4*)(gBl  + koff);
    }
    bfrag Afh[2], Afl[2], Bfh[4], Bfl[4];
    #pragma unroll
    for (int mt=0;mt<2;++mt){
      const int m = wv*32 + mt*16 + lane15;
      Afh[mt] = *(const bfrag*)&Ah_s[m*32 + quad*8];
      Afl[mt] = *(const bfrag*)&Al_s[m*32 + quad*8];
    }
    #pragma unroll
    for (int nt=0;nt<4;++nt){
      const int oc = nt*16 + lane15;
      Bfh[nt] = *(const bfrag*)&Bh_s[oc*32 + quad*8];
      Bfl[nt] = *(const bfrag*)&Bl_s[oc*32 + quad*8];
    }
    #pragma unroll
    for (int mt=0;mt<2;++mt)
      #pragma unroll
      for (int nt=0;nt<4;++nt){
        acc[mt][nt] = __builtin_amdgcn_mfma_f32_16x16x32_bf16(Afh[mt], Bfh[nt], acc[mt][nt], 0, 0, 0);
        acc[mt][nt] = __builtin_amdgcn_mfma_f32_16x16x32_bf16(Afl[mt], Bfh[nt], acc[mt][nt], 0, 0, 0);
        acc[mt][nt] = __builtin_amdgcn_mfma_f32_16x16x32_bf16(Afh[mt], Bfl[nt], acc[mt][nt], 0, 0, 0);
      }
    __syncthreads();
  }
  #pragma unroll
  for (int nt=0;nt<4;++nt){
    float m = NEG_INF;
    #pragma unroll
    for (int mt=0;mt<2;++mt)
      #pragma unroll
      for (int r=0;r<4;++r) m = fmaxf(m, acc[mt][nt][r]);
    m = fmaxf(m, __shfl_xor(m, 16, 64));
    m = fmaxf(m, __shfl_xor(m, 32, 64));
    if (quad == 0){
      const int o = o0 + nt*16 + lane15;
      float vv = fmaxf(m * bn_scale(g[o]) + bb[o], 0.f);
      atomicMax((int*)&out5[(size_t)b*1024 + o], __float_as_int(vv));
    }
  }
}

__global__ void zero_kernel(float* __restrict__ p, int nfloats){
  int i = blockIdx.x*blockDim.x + threadIdx.x;
  if (i < nfloats) p[i] = 0.f;
}

// ---------------- FC layers: one wave per (b,o), coalesced lane-strided reads ----------
__global__ __launch_bounds__(256) void fc_wave_kernel(const float* __restrict__ in,
    const float* __restrict__ w, const float* __restrict__ g, const float* __restrict__ bb,
    float* __restrict__ out, int IN, int O){
  const int wid = (blockIdx.x*256 + threadIdx.x) >> 6;
  const int lane = threadIdx.x & 63;
  if (wid >= BATCH*O) return;
  const int b = wid / O, o = wid - b*O;
  const float* inb = in + (size_t)b*IN;
  const float* wo  = w + (size_t)o*IN;
  float s = 0.f;
  for (int c = lane; c < IN; c += 64) s += inb[c]*wo[c];   // coalesced across the wave
  s = wave_sum(s);
  if (lane == 0){
    if (g){ s = s*bn_scale(g[o]) + bb[o]; s = fmaxf(s, 0.f); }
    out[wid] = s;
  }
}

extern "C" void kernel_launch(void* const* d_in, const int* in_sizes, int n_in,
                              void* d_out, int out_size, void* d_ws, size_t ws_size,
                              hipStream_t stream){
  const float* x   = (const float*)d_in[0];
  const float* w1  = (const float*)d_in[1];
  const float* w2  = (const float*)d_in[2];
  const float* w3  = (const float*)d_in[3];
  const float* w4  = (const float*)d_in[4];
  const float* w5  = (const float*)d_in[5];
  const float* fw1 = (const float*)d_in[6];
  const float* fw2 = (const float*)d_in[7];
  const float* fw3 = (const float*)d_in[8];
  const float* g1 = (const float*)d_in[9];  const float* b1 = (const float*)d_in[10];
  const float* g2 = (const float*)d_in[11]; const float* b2 = (const float*)d_in[12];
  const float* g3 = (const float*)d_in[13]; const float* b3 = (const float*)d_in[14];
  const float* g4 = (const float*)d_in[15]; const float* b4 = (const float*)d_in[16];
  const float* g5 = (const float*)d_in[17]; const float* b5 = (const float*)d_in[18];
  const float* g6 = (const float*)d_in[19]; const float* b6 = (const float*)d_in[20];
  const float* g7 = (const float*)d_in[21]; const float* b7 = (const float*)d_in[22];

  float* ws = (float*)d_ws;
  size_t off = 0;
  unsigned short* xcat_hi = (unsigned short*)(ws + off); off += (size_t)BATCH*256*NPTS; // B*N*512 bf16
  unsigned short* xcat_lo = (unsigned short*)(ws + off); off += (size_t)BATCH*256*NPTS;
  float* x1T = ws + off; off += (size_t)BATCH*64*NPTS;
  float* x2T = ws + off; off += (size_t)BATCH*64*NPTS;
  float* x3T = ws + off; off += (size_t)BATCH*128*NPTS;
  float* x4T = ws + off; off += (size_t)BATCH*256*NPTS;   // == NPTS*NPTS floats
  float* Dbuf = x4T;   // alias: x4T written only after the last knn select finishes
  float* xT0 = ws + off; off += (size_t)BATCH*3*NPTS;
  float* sq  = ws + off; off += (size_t)BATCH*NPTS;
  int*  idx  = (int*)(ws + off); off += (size_t)BATCH*NPTS*KNN;
  float* out5 = ws + off; off += BATCH*1024;
  float* h6 = ws + off;   off += BATCH*512;
  float* h7 = ws + off;   off += BATCH*256;
  float* wnT1 = ws + off; off += 3*64;
  float* wdT1 = ws + off; off += 3*64;
  unsigned short* wn2 = (unsigned short*)(ws + off); off += 64*64/2;
  unsigned short* wd2 = (unsigned short*)(ws + off); off += 64*64/2;
  unsigned short* wn3 = (unsigned short*)(ws + off); off += 128*64/2;
  unsigned short* wd3 = (unsigned short*)(ws + off); off += 128*64/2;
  unsigned short* wn4 = (unsigned short*)(ws + off); off += 256*128/2;
  unsigned short* wd4 = (unsigned short*)(ws + off); off += 256*128/2;
  unsigned short* w5hi = (unsigned short*)(ws + off); off += 1024*512/2;
  unsigned short* w5lo = (unsigned short*)(ws + off); off += 1024*512/2;

  dim3 gridKNN(NPTS/8, BATCH);
  dim3 gridEC(NPTS/4, BATCH);
  dim3 gridDG(NPTS/128, NPTS/64);

  // layer 1 (C=3 -> 64, fp32, bit-exact knn)
  xt0_kernel<<<64, 256, 0, stream>>>(x, xT0);
  sqnorm_kernel<<<64, 256, 0, stream>>>(x, sq, 3);
  knn_kernel<3><<<gridKNN, 256, 0, stream>>>(x, sq, idx);
  wprep_kernel<<<1, 256, 0, stream>>>(w1, wnT1, wdT1, 64, 3);
  edgeconv1_kernel<<<gridEC, 256, 0, stream>>>(xT0, idx, wnT1, wdT1, g1, b1, x1T);
  // layer 2 (C=64 -> 64): xsplit cols 0..63, MFMA dist GEMM + select
  xsplit_kernel<<<(BATCH*NPTS*16)/256, 256, 0, stream>>>(x1T, xcat_hi, xcat_lo, 16);
  sqnorm_pm_kernel<<<64, 256, 0, stream>>>(x1T, sq, 64);
  for (int b=0; b<BATCH; ++b){
    distgemm<64><<<gridDG, 256, 0, stream>>>(xcat_hi + (size_t)b*NPTS*512,
                                             xcat_lo + (size_t)b*NPTS*512,
                                             sq + (size_t)b*NPTS, Dbuf);
    knn_select<<<NPTS/4, 256, 0, stream>>>(Dbuf, idx + (size_t)b*NPTS*KNN);
  }
  wprep_bf_kernel<<<16, 256, 0, stream>>>(w2, wn2, wd2, 64, 64);
  edgeconv_mfma<64,64><<<gridEC, 256, 0, stream>>>(x1T, idx, wn2, wd2, g2, b2, x2T);
  // layer 3 (C=64 -> 128): cols 64..127
  xsplit_kernel<<<(BATCH*NPTS*16)/256, 256, 0, stream>>>(x2T, xcat_hi + 64, xcat_lo + 64, 16);
  sqnorm_pm_kernel<<<64, 256, 0, stream>>>(x2T, sq, 64);
  for (int b=0; b<BATCH; ++b){
    distgemm<64><<<gridDG, 256, 0, stream>>>(xcat_hi + (size_t)b*NPTS*512 + 64,
                                             xcat_lo + (size_t)b*NPTS*512 + 64,
                                             sq + (size_t)b*NPTS, Dbuf);
    knn_select<<<NPTS/4, 256, 0, stream>>>(Dbuf, idx + (size_t)b*NPTS*KNN);
  }
  wprep_bf_kernel<<<32, 256, 0, stream>>>(w3, wn3, wd3, 128, 64);
  edgeconv_mfma<64,128><<<gridEC, 256, 0, stream>>>(x2T, idx, wn3, wd3, g3, b3, x3T);
  // layer 4 (C=128 -> 256): cols 128..255
  xsplit_kernel<<<(BATCH*NPTS*32)/256, 256, 0, stream>>>(x3T, xcat_hi + 128, xcat_lo + 128, 32);
  sqnorm_pm_kernel<<<64, 256, 0, stream>>>(x3T, sq, 128);
  for (int b=0; b<BATCH; ++b){
    distgemm<128><<<gridDG, 256, 0, stream>>>(xcat_hi + (size_t)b*NPTS*512 + 128,
                                              xcat_lo + (size_t)b*NPTS*512 + 128,
                                              sq + (size_t)b*NPTS, Dbuf);
    knn_select<<<NPTS/4, 256, 0, stream>>>(Dbuf, idx + (size_t)b*NPTS*KNN);
  }
  wprep_bf_kernel<<<128, 256, 0, stream>>>(w4, wn4, wd4, 256, 128);
  edgeconv_mfma<128,256><<<gridEC, 256, 0, stream>>>(x3T, idx, wn4, wd4, g4, b4, x4T);
  // conv5: xsplit cols 256..511, split-bf16 MFMA GEMM + global max over n
  xsplit_kernel<<<(BATCH*NPTS*64)/256, 256, 0, stream>>>(x4T, xcat_hi + 256, xcat_lo + 256, 64);
  bfsplit_kernel<<<512, 256, 0, stream>>>(w5, w5hi, w5lo, 1024*512/4);
  zero_kernel<<<32, 256, 0, stream>>>(out5, BATCH*1024);
  conv5_v3<<<dim3(BATCH*NPTS/128, 16), 256, 0, stream>>>(xcat_hi, xcat_lo, w5hi, w5lo, g5, b5, out5);
  // FC head (wave-per-output, coalesced)
  fc_wave_kernel<<<(BATCH*512*64)/256, 256, 0, stream>>>(out5, fw1, g6, b6, h6, 1024, 512);
  fc_wave_kernel<<<(BATCH*256*64)/256, 256, 0, stream>>>(h6, fw2, g7, b7, h7, 512, 256);
  fc_wave_kernel<<<(BATCH*40*64 + 255)/256, 256, 0, stream>>>(h7, fw3, nullptr, nullptr, (float*)d_out, 256, 40);
}

// Round 19
// 870.358 us; speedup vs baseline: 1.2260x; 1.2260x over previous
//
#include <hip/hip_runtime.h>
#include <hip/hip_bf16.h>
#include <math.h>

#define BATCH 8
#define NPTS  2048
#define KNN   20
#define NEG_INF (-3.402823466e38f)

static __device__ __forceinline__ float bn_scale(float g){ return g * rsqrtf(1.0f + 1e-5f); }

// bf16 round-to-nearest-even
static __device__ __forceinline__ unsigned short bf16r(float f){
  unsigned int u = __float_as_uint(f);
  unsigned int r = (u + 0x7fffu + ((u >> 16) & 1u)) >> 16;
  return (unsigned short)r;
}
static __device__ __forceinline__ float bf2f(unsigned short h){
  return __uint_as_float((unsigned int)h << 16);
}
// ordered-int encode/decode for float max via atomicMax(uint)
static __device__ __forceinline__ unsigned int fenc(float f){
  unsigned int u = __float_as_uint(f);
  return (u & 0x80000000u) ? ~u : (u | 0x80000000u);
}
static __device__ __forceinline__ float fdec(unsigned int e){
  return __uint_as_float((e & 0x80000000u) ? (e & 0x7fffffffu) : ~e);
}

using bfrag = __attribute__((ext_vector_type(8))) short;  // 8 bf16 (4 VGPRs)
using f32x4 = __attribute__((ext_vector_type(4))) float;  // 4 fp32 acc
using f32x2 = __attribute__((ext_vector_type(2))) float;  // packed pair -> v_pk_fma_f32

// ---- DPP-based wave argmax (lexicographic value desc, idx asc); winner in lane 63 ----
template<int CTRL>
static __device__ __forceinline__ void dpp_amax(float &bv, int &bi){
  int ov_i = __builtin_amdgcn_update_dpp(__float_as_int(NEG_INF), __float_as_int(bv),
                                         CTRL, 0xf, 0xf, false);
  int oi   = __builtin_amdgcn_update_dpp(0x7fffffff, bi, CTRL, 0xf, 0xf, false);
  float ov = __int_as_float(ov_i);
  if (ov > bv || (ov == bv && oi < bi)){ bv = ov; bi = oi; }
}
static __device__ __forceinline__ int wave_argmax_idx(float bv, int bi){
  dpp_amax<0x111>(bv, bi);   // row_shr:1
  dpp_amax<0x112>(bv, bi);   // row_shr:2
  dpp_amax<0x114>(bv, bi);   // row_shr:4
  dpp_amax<0x118>(bv, bi);   // row_shr:8
  dpp_amax<0x142>(bv, bi);   // row_bcast:15
  dpp_amax<0x143>(bv, bi);   // row_bcast:31
  return __builtin_amdgcn_readlane(bi, 63);
}
// ---- DPP wave sum (identity 0.0 injected); total broadcast from lane 63 ----
template<int CTRL>
static __device__ __forceinline__ float dpp_fadd(float v){
  int ov = __builtin_amdgcn_update_dpp(0, __float_as_int(v), CTRL, 0xf, 0xf, false);
  return v + __int_as_float(ov);
}
static __device__ __forceinline__ float wave_sum(float v){
  v = dpp_fadd<0x111>(v); v = dpp_fadd<0x112>(v);
  v = dpp_fadd<0x114>(v); v = dpp_fadd<0x118>(v);
  v = dpp_fadd<0x142>(v); v = dpp_fadd<0x143>(v);
  return __int_as_float(__builtin_amdgcn_readlane(__float_as_int(v), 63));
}

// ---------------- squared norms per point (reads channel-major [C][N]) ----------------
__global__ void sqnorm_kernel(const float* __restrict__ X, float* __restrict__ sq, int C){
  int i = blockIdx.x*blockDim.x + threadIdx.x;
  if (i >= BATCH*NPTS) return;
  int b = i / NPTS, n = i - b*NPTS;
  const float* xb = X + (size_t)b*C*NPTS + n;
  float s = 0.f;
  for (int c=0;c<C;++c){ float v = xb[(size_t)c*NPTS]; s += v*v; }
  sq[i] = s;
}

// ---------------- kNN v10 (r17 measured best): pk-f32 dist + top-4 queue + DPP argmax --
template<int C>
__global__ __launch_bounds__(256, 2) void knn_kernel(const float* __restrict__ X,
                                                     const float* __restrict__ sq,
                                                     int* __restrict__ idxout){
  const int b = blockIdx.y;
  const int n0 = blockIdx.x * 8;
  const int t = threadIdx.x;
  __shared__ __align__(16) float dist[4][NPTS];
  __shared__ float ctrs[C][8];
  __shared__ float sqn[8];
  const float* xb = X + (size_t)b*C*NPTS;
  for (int i=t; i<C*8; i+=256){
    int c = i >> 3, p = i & 7;
    ctrs[c][p] = xb[(size_t)c*NPTS + n0 + p];
  }
  if (t < 8) sqn[t] = sq[b*NPTS + n0 + t];
  __syncthreads();

  const int m0 = t * 8;
  f32x2 acc2[8][4];
  #pragma unroll
  for (int i=0;i<8;++i)
    #pragma unroll
    for (int j=0;j<4;++j) acc2[i][j] = (f32x2){0.f, 0.f};
  for (int c=0;c<C;++c){
    const float4 xa = *(const float4*)&xb[(size_t)c*NPTS + m0];
    const float4 xc = *(const float4*)&xb[(size_t)c*NPTS + m0 + 4];
    const f32x2 xm2[4] = {(f32x2){xa.x,xa.y}, (f32x2){xa.z,xa.w},
                          (f32x2){xc.x,xc.y}, (f32x2){xc.z,xc.w}};
    #pragma unroll
    for (int i=0;i<8;++i){
      const float cv = ctrs[c][i];
      const f32x2 cv2 = (f32x2){cv, cv};
      #pragma unroll
      for (int j=0;j<4;++j) acc2[i][j] += cv2*xm2[j];   // v_pk_fma_f32
    }
  }
  {
    const float4 sa = *(const float4*)&sq[b*NPTS + m0];
    const float4 sb = *(const float4*)&sq[b*NPTS + m0 + 4];
    const f32x2 sm2[4] = {(f32x2){sa.x,sa.y}, (f32x2){sa.z,sa.w},
                          (f32x2){sb.x,sb.y}, (f32x2){sb.z,sb.w}};
    #pragma unroll
    for (int i=0;i<8;++i){
      const float si = sqn[i];
      const f32x2 si2 = (f32x2){si, si};
      #pragma unroll
      for (int j=0;j<4;++j) acc2[i][j] = (f32x2){2.f,2.f}*acc2[i][j] - si2 - sm2[j];
    }
  }

  const int wv = t >> 6, lane = t & 63;
  #pragma unroll
  for (int rep=0; rep<2; ++rep){
    #pragma unroll
    for (int i=0;i<4;++i){
      const int r = rep*4 + i;
      *(float4*)&dist[i][m0]   = make_float4(acc2[r][0].x, acc2[r][0].y, acc2[r][1].x, acc2[r][1].y);
      *(float4*)&dist[i][m0+4] = make_float4(acc2[r][2].x, acc2[r][2].y, acc2[r][3].x, acc2[r][3].y);
    }
    __syncthreads();
    // initial scan: per-lane sorted top-4 (value desc, idx asc) in registers
    float s0=NEG_INF,s1=NEG_INF,s2=NEG_INF,s3=NEG_INF;
    int   i0=0x7fffffff,i1=0x7fffffff,i2=0x7fffffff,i3=0x7fffffff;
    #pragma unroll
    for (int j=0;j<32;++j){
      const float v = dist[wv][lane + 64*j];
      const int   m = lane + 64*j;
      const bool b0 = v > s0, b1 = v > s1, b2 = v > s2, b3 = v > s3;  // strict: stable ties
      const float n0 = b0 ? v : s0;            const int q0 = b0 ? m : i0;
      const float n1 = b0 ? s0 : (b1 ? v : s1); const int q1 = b0 ? i0 : (b1 ? m : i1);
      const float n2 = b1 ? s1 : (b2 ? v : s2); const int q2 = b1 ? i1 : (b2 ? m : i2);
      const float n3 = b2 ? s2 : (b3 ? v : s3); const int q3 = b2 ? i2 : (b3 ? m : i3);
      s0=n0;s1=n1;s2=n2;s3=n3; i0=q0;i1=q1;i2=q2;i3=q3;
    }
    int rem = 4;
    int* row = idxout + ((size_t)b*NPTS + n0 + rep*4 + wv)*KNN;
    for (int sel=0; sel<KNN; ++sel){
      const int widx = wave_argmax_idx(s0, i0);   // DPP reduction over queue heads
      if (lane == 0) row[sel] = widx;
      if ((widx & 63) == lane){
        const float lastv = s0; const int lasti = i0;
        s0=s1;i0=i1; s1=s2;i1=i2; s2=s3;i2=i3;
        rem--;
        if (rem == 0){
          float nv = NEG_INF; int ni = 0x7fffffff;
          #pragma unroll
          for (int j=0;j<32;++j){
            const float vv = dist[wv][lane + 64*j];
            const int   mi = lane + 64*j;
            const bool ok = (vv < lastv) || (vv == lastv && mi > lasti);
            if (ok && vv > nv){ nv = vv; ni = mi; }
          }
          s0 = nv; i0 = ni; rem = 1;
        }
      }
    }
    __syncthreads();
  }
}

// ---------------- fp32 weight prep (layer 1 only): wnT[c][o], wdT[c][o] ----------------
__global__ void wprep_kernel(const float* __restrict__ w, float* __restrict__ wnT,
                             float* __restrict__ wdT, int O, int C){
  int i = blockIdx.x*blockDim.x + threadIdx.x;
  if (i >= O*C) return;
  int c = i / O, o = i - c*O;
  float a = w[(size_t)o*2*C + c];
  wnT[(size_t)c*O + o] = a;
  wdT[(size_t)c*O + o] = w[(size_t)o*2*C + C + c] - a;
}

// ---------------- bf16 weight prep (layers 2-4): wn[o][c], wd[o][c] (k contiguous) -----
__global__ void wprep_bf_kernel(const float* __restrict__ w, unsigned short* __restrict__ wn,
                                unsigned short* __restrict__ wd, int O, int C){
  int i = blockIdx.x*blockDim.x + threadIdx.x;
  if (i >= O*C) return;
  int o = i / C, c = i - o*C;
  float a = w[(size_t)o*2*C + c];
  float d = w[(size_t)o*2*C + C + c] - a;
  wn[(size_t)o*C + c] = bf16r(a);
  wd[(size_t)o*C + c] = bf16r(d);
}

// ---------------- split-bf16 weight convert (conv5): hi = bf16(w), lo = bf16(w-hi) ------
__global__ void bfsplit_kernel(const float* __restrict__ in, unsigned short* __restrict__ hi,
                               unsigned short* __restrict__ lo, int nq){
  int i = blockIdx.x*blockDim.x + threadIdx.x;
  if (i >= nq) return;
  float4 v = *(const float4*)&in[(size_t)i*4];
  unsigned short h0=bf16r(v.x), h1=bf16r(v.y), h2=bf16r(v.z), h3=bf16r(v.w);
  unsigned short l0=bf16r(v.x-bf2f(h0)), l1=bf16r(v.y-bf2f(h1)),
                 l2=bf16r(v.z-bf2f(h2)), l3=bf16r(v.w-bf2f(h3));
  *(uint2*)&hi[(size_t)i*4] = make_uint2((unsigned)h0|((unsigned)h1<<16), (unsigned)h2|((unsigned)h3<<16));
  *(uint2*)&lo[(size_t)i*4] = make_uint2((unsigned)l0|((unsigned)l1<<16), (unsigned)l2|((unsigned)l3<<16));
}

// ---------------- xcat: concat x1T..x4T -> split-bf16 [b][n][512] ----------------
__global__ __launch_bounds__(256) void xcat_kernel(const float* __restrict__ x1T,
    const float* __restrict__ x2T, const float* __restrict__ x3T, const float* __restrict__ x4T,
    unsigned short* __restrict__ xhi, unsigned short* __restrict__ xlo){
  int i = blockIdx.x*blockDim.x + threadIdx.x;   // quad index over B*N*128
  if (i >= BATCH*NPTS*128) return;
  int q = i & 127, bn_ = i >> 7;
  int k = q*4;
  const float* src; int kk;
  if (k < 64)      { src = x1T + (size_t)bn_*64;  kk = k; }
  else if (k <128) { src = x2T + (size_t)bn_*64;  kk = k-64; }
  else if (k <256) { src = x3T + (size_t)bn_*128; kk = k-128; }
  else             { src = x4T + (size_t)bn_*256; kk = k-256; }
  float4 v = *(const float4*)&src[kk];
  unsigned short h0=bf16r(v.x), h1=bf16r(v.y), h2=bf16r(v.z), h3=bf16r(v.w);
  unsigned short l0=bf16r(v.x-bf2f(h0)), l1=bf16r(v.y-bf2f(h1)),
                 l2=bf16r(v.z-bf2f(h2)), l3=bf16r(v.w-bf2f(h3));
  *(uint2*)&xhi[(size_t)i*4] = make_uint2((unsigned)h0|((unsigned)h1<<16), (unsigned)h2|((unsigned)h3<<16));
  *(uint2*)&xlo[(size_t)i*4] = make_uint2((unsigned)l0|((unsigned)l1<<16), (unsigned)l2|((unsigned)l3<<16));
}

// ---------------- generic tiled transpose: in[R][Cc] -> out[Cc][R], per z-slice ----------------
__global__ __launch_bounds__(256) void transpose2d_kernel(const float* __restrict__ in,
    float* __restrict__ out, int R, int Cc){
  __shared__ float tile[32][33];
  const size_t boff = (size_t)blockIdx.z * (size_t)R * Cc;
  const int c0 = blockIdx.x*32, r0 = blockIdx.y*32;
  const int tx = threadIdx.x & 31, ty = threadIdx.x >> 5;
  #pragma unroll
  for (int j=0;j<4;++j){
    int r = ty*4 + j;
    tile[r][tx] = in[boff + (size_t)(r0+r)*Cc + c0 + tx];
  }
  __syncthreads();
  #pragma unroll
  for (int j=0;j<4;++j){
    int r = ty*4 + j;
    out[boff + (size_t)(c0+r)*R + r0 + tx] = tile[tx][r];
  }
}

// ---------------- x -> xT0 [N][3] ----------------
__global__ void xt0_kernel(const float* __restrict__ x, float* __restrict__ xT0){
  int i = blockIdx.x*blockDim.x + threadIdx.x;
  if (i >= BATCH*NPTS) return;
  int b = i / NPTS, n = i - b*NPTS;
  const float* xb = x + (size_t)b*3*NPTS;
  float v0 = xb[n], v1 = xb[NPTS + n], v2 = xb[2*NPTS + n];
  float* o = xT0 + ((size_t)b*NPTS + n)*3;
  o[0]=v0; o[1]=v1; o[2]=v2;
}

// ---------------- edge conv layer 1 (C=3, fp32): 4 points per block ----------------
__global__ __launch_bounds__(256) void edgeconv1_kernel(const float* __restrict__ xT0,
    const int* __restrict__ idx, const float* __restrict__ wnT, const float* __restrict__ wdT,
    const float* __restrict__ g, const float* __restrict__ bb, float* __restrict__ outT){
  const int b = blockIdx.y, n0 = blockIdx.x*4, t = threadIdx.x;
  __shared__ float nbr[4][KNN][3];
  __shared__ float ctr[4][3];
  __shared__ int   idxs[4][KNN];
  const float* xb = xT0 + (size_t)b*NPTS*3;
  if (t < 4*KNN) idxs[t/KNN][t%KNN] = idx[((size_t)b*NPTS + n0 + t/KNN)*KNN + (t%KNN)];
  if (t >= 128 && t < 140){ int i = t-128; ctr[i/3][i%3] = xb[(size_t)(n0 + i/3)*3 + i%3]; }
  __syncthreads();
  for (int i=t; i<4*KNN*3; i+=256){
    int p = i/(KNN*3), r = i - p*(KNN*3), k = r/3, c = r - k*3;
    nbr[p][k][c] = xb[(size_t)idxs[p][k]*3 + c];
  }
  __syncthreads();
  const int p = t >> 6, o = t & 63;
  const float wn0 = wnT[o], wn1 = wnT[64+o], wn2 = wnT[128+o];
  const float cst = ctr[p][0]*wdT[o] + ctr[p][1]*wdT[64+o] + ctr[p][2]*wdT[128+o];
  float best = NEG_INF;
  #pragma unroll
  for (int k=0;k<KNN;++k){
    float a = nbr[p][k][0]*wn0 + nbr[p][k][1]*wn1 + nbr[p][k][2]*wn2;
    best = fmaxf(best, a);
  }
  float vv = (best + cst) * bn_scale(g[o]) + bb[o];
  outT[((size_t)b*NPTS + n0 + p)*64 + o] = fmaxf(vv, 0.f);
}

// ---------------- edge conv MFMA (bf16): block = 4 points ----------------
// r19 tweak: quad pairs (0,1) and (2,3) always share p (straddle only between quads 1|2),
// so pre-reduce max via shfl_xor(16) and atomicMax from even quads only (halves LDS
// same-address atomic contention; bit-exact since max is associative and fenc monotone).
template<int C, int O>
__global__ __launch_bounds__(256) void edgeconv_mfma(const float* __restrict__ xT,
    const int* __restrict__ idx,
    const unsigned short* __restrict__ wn_bf, const unsigned short* __restrict__ wd_bf,
    const float* __restrict__ g, const float* __restrict__ bb, float* __restrict__ outT){
  constexpr int ROWS = 112;        // 7 m-tiles of 16
  constexpr int CP   = C + 8;      // padded row (bf16): 16B-aligned stride, conflict-free b128
  constexpr int KS   = C / 32;     // k-steps per tile
  constexpr int NTW  = O / 64;     // n-tiles per wave (O/16 tiles over 4 waves)
  __shared__ __align__(16) unsigned short A[ROWS][CP];
  __shared__ unsigned int res[4][O];
  __shared__ float cst_s[4][O];
  __shared__ int idxs[4][KNN];
  const int b = blockIdx.y, n0 = blockIdx.x*4, t = threadIdx.x;
  const float* xTb = xT + (size_t)b*NPTS*C;
  if (t < 4*KNN) idxs[t/KNN][t%KNN] = idx[((size_t)b*NPTS + n0 + t/KNN)*KNN + (t%KNN)];
  for (int i=t; i<4*O; i+=256) res[i/O][i & (O-1)] = 0u;   // 0 < fenc(any finite)
  __syncthreads();
  for (int i=t; i<ROWS*(C/4); i+=256){
    int r = i/(C/4), c4 = i - r*(C/4);
    float4 v = make_float4(0.f,0.f,0.f,0.f);
    if (r < 96){
      int p = r/24, kk = r - p*24;
      int src = idxs[p][kk < KNN ? kk : 0];        // pad rows duplicate nbr 0 (max-neutral)
      v = *(const float4*)&xTb[(size_t)src*C + c4*4];
    } else if (r < 100){
      v = *(const float4*)&xTb[(size_t)(n0 + (r-96))*C + c4*4];
    }
    unsigned int lo = (unsigned int)bf16r(v.x) | ((unsigned int)bf16r(v.y) << 16);
    unsigned int hi = (unsigned int)bf16r(v.z) | ((unsigned int)bf16r(v.w) << 16);
    *(uint2*)&A[r][c4*4] = make_uint2(lo, hi);
  }
  __syncthreads();

  const int wv = t >> 6, l = t & 63;
  const int lane15 = l & 15, quad = l >> 4;
  bfrag Bn[NTW][KS];
  #pragma unroll
  for (int nt=0; nt<NTW; ++nt){
    const int col = (wv*NTW + nt)*16 + lane15;
    #pragma unroll
    for (int s=0; s<KS; ++s)
      Bn[nt][s] = *(const bfrag*)&wn_bf[(size_t)col*C + s*32 + quad*8];
  }
  #pragma unroll
  for (int mt=0; mt<7; ++mt){
    bfrag Af[KS];
    #pragma unroll
    for (int s=0; s<KS; ++s)
      Af[s] = *(const bfrag*)&A[mt*16 + lane15][s*32 + quad*8];
    if (mt < 6){
      const int rbase = mt*16 + quad*4;
      const int p = rbase / 24;
      #pragma unroll
      for (int nt=0; nt<NTW; ++nt){
        f32x4 acc = {0.f,0.f,0.f,0.f};
        #pragma unroll
        for (int s=0; s<KS; ++s)
          acc = __builtin_amdgcn_mfma_f32_16x16x32_bf16(Af[s], Bn[nt][s], acc, 0, 0, 0);
        float m = fmaxf(fmaxf(acc[0], acc[1]), fmaxf(acc[2], acc[3]));
        m = fmaxf(m, __shfl_xor(m, 16, 64));   // partner quad shares p
        const int col = (wv*NTW + nt)*16 + lane15;
        if ((quad & 1) == 0) atomicMax(&res[p][col], fenc(m));
      }
    } else {
      #pragma unroll
      for (int nt=0; nt<NTW; ++nt){
        const int col = (wv*NTW + nt)*16 + lane15;
        f32x4 acc = {0.f,0.f,0.f,0.f};
        #pragma unroll
        for (int s=0; s<KS; ++s){
          bfrag Bd = *(const bfrag*)&wd_bf[(size_t)col*C + s*32 + quad*8];
          acc = __builtin_amdgcn_mfma_f32_16x16x32_bf16(Af[s], Bd, acc, 0, 0, 0);
        }
        if (quad == 0){
          #pragma unroll
          for (int r=0;r<4;++r) cst_s[r][col] = acc[r];
        }
      }
    }
  }
  __syncthreads();
  for (int i=t; i<4*O; i+=256){
    int p = i/O, o = i - p*O;
    float mx = fdec(res[p][o]);
    float vv = (mx + cst_s[p][o]) * bn_scale(g[o]) + bb[o];
    outT[((size_t)b*NPTS + n0 + p)*O + o] = fmaxf(vv, 0.f);
  }
}

// ---------------- conv5 v3: LDS-staged split-bf16 MFMA GEMM + max over n ----------------
__global__ __launch_bounds__(256) void conv5_v3(const unsigned short* __restrict__ xhi,
    const unsigned short* __restrict__ xlo, const unsigned short* __restrict__ whi,
    const unsigned short* __restrict__ wlo, const float* __restrict__ g,
    const float* __restrict__ bb, float* __restrict__ out5){
  __shared__ __align__(16) unsigned short Ah_s[128*32];
  __shared__ __align__(16) unsigned short Al_s[128*32];
  __shared__ __align__(16) unsigned short Bh_s[64*32];
  __shared__ __align__(16) unsigned short Bl_s[64*32];
  const int t = threadIdx.x;
  const int row0 = blockIdx.x*128, o0 = blockIdx.y*64;
  const int b = row0 / NPTS;   // 128 | NPTS, so a block never straddles batches
  const int wv = t >> 6, l = t & 63, lane15 = l & 15, quad = l >> 4;
  const int ar = t >> 2, ac = (t & 3)*8;
  const unsigned short* gAh0 = xhi + (size_t)(row0 + ar)*512 + ac;
  const unsigned short* gAh1 = xhi + (size_t)(row0 + 64 + ar)*512 + ac;
  const unsigned short* gAl0 = xlo + (size_t)(row0 + ar)*512 + ac;
  const unsigned short* gAl1 = xlo + (size_t)(row0 + 64 + ar)*512 + ac;
  const unsigned short* gBh  = whi + (size_t)(o0 + ar)*512 + ac;
  const unsigned short* gBl  = wlo + (size_t)(o0 + ar)*512 + ac;

  uint4 pf0 = *(const uint4*)gAh0;
  uint4 pf1 = *(const uint4*)gAh1;
  uint4 pf2 = *(const uint4*)gAl0;
  uint4 pf3 = *(const uint4*)gAl1;
  uint4 pf4 = *(const uint4*)gBh;
  uint4 pf5 = *(const uint4*)gBl;

  f32x4 acc[2][4];
  #pragma unroll
  for (int mt=0;mt<2;++mt)
    #pragma unroll
    for (int nt=0;nt<4;++nt) acc[mt][nt] = (f32x4){0.f,0.f,0.f,0.f};

  for (int ks=0; ks<16; ++ks){
    *(uint4*)&Ah_s[t*8]        = pf0;
    *(uint4*)&Ah_s[2048 + t*8] = pf1;
    *(uint4*)&Al_s[t*8]        = pf2;
    *(uint4*)&Al_s[2048 + t*8] = pf3;
    *(uint4*)&Bh_s[t*8]        = pf4;
    *(uint4*)&Bl_s[t*8]        = pf5;
    __syncthreads();
    if (ks < 15){
      const int koff = (ks+1)*32;
      pf0 = *(const uint4*)(gAh0 + koff);
      pf1 = *(const uint4*)(gAh1 + koff);
      pf2 = *(const uint4*)(gAl0 + koff);
      pf3 = *(const uint4*)(gAl1 + koff);
      pf4 = *(const uint4*)(gBh  + koff);
      pf5 = *(const uint4*)(gBl  + koff);
    }
    bfrag Afh[2], Afl[2], Bfh[4], Bfl[4];
    #pragma unroll
    for (int mt=0;mt<2;++mt){
      const int m = wv*32 + mt*16 + lane15;
      Afh[mt] = *(const bfrag*)&Ah_s[m*32 + quad*8];
      Afl[mt] = *(const bfrag*)&Al_s[m*32 + quad*8];
    }
    #pragma unroll
    for (int nt=0;nt<4;++nt){
      const int oc = nt*16 + lane15;
      Bfh[nt] = *(const bfrag*)&Bh_s[oc*32 + quad*8];
      Bfl[nt] = *(const bfrag*)&Bl_s[oc*32 + quad*8];
    }
    #pragma unroll
    for (int mt=0;mt<2;++mt)
      #pragma unroll
      for (int nt=0;nt<4;++nt){
        acc[mt][nt] = __builtin_amdgcn_mfma_f32_16x16x32_bf16(Afh[mt], Bfh[nt], acc[mt][nt], 0, 0, 0);
        acc[mt][nt] = __builtin_amdgcn_mfma_f32_16x16x32_bf16(Afl[mt], Bfh[nt], acc[mt][nt], 0, 0, 0);
        acc[mt][nt] = __builtin_amdgcn_mfma_f32_16x16x32_bf16(Afh[mt], Bfl[nt], acc[mt][nt], 0, 0, 0);
      }
    __syncthreads();
  }
  #pragma unroll
  for (int nt=0;nt<4;++nt){
    float m = NEG_INF;
    #pragma unroll
    for (int mt=0;mt<2;++mt)
      #pragma unroll
      for (int r=0;r<4;++r) m = fmaxf(m, acc[mt][nt][r]);
    m = fmaxf(m, __shfl_xor(m, 16, 64));
    m = fmaxf(m, __shfl_xor(m, 32, 64));
    if (quad == 0){
      const int o = o0 + nt*16 + lane15;
      float vv = fmaxf(m * bn_scale(g[o]) + bb[o], 0.f);
      atomicMax((int*)&out5[(size_t)b*1024 + o], __float_as_int(vv));
    }
  }
}

__global__ void zero_kernel(float* __restrict__ p, int nfloats){
  int i = blockIdx.x*blockDim.x + threadIdx.x;
  if (i < nfloats) p[i] = 0.f;
}

// ---------------- FC layers: one wave per (b,o), coalesced lane-strided reads ----------
__global__ __launch_bounds__(256) void fc_wave_kernel(const float* __restrict__ in,
    const float* __restrict__ w, const float* __restrict__ g, const float* __restrict__ bb,
    float* __restrict__ out, int IN, int O){
  const int wid = (blockIdx.x*256 + threadIdx.x) >> 6;
  const int lane = threadIdx.x & 63;
  if (wid >= BATCH*O) return;
  const int b = wid / O, o = wid - b*O;
  const float* inb = in + (size_t)b*IN;
  const float* wo  = w + (size_t)o*IN;
  float s = 0.f;
  for (int c = lane; c < IN; c += 64) s += inb[c]*wo[c];   // coalesced across the wave
  s = wave_sum(s);
  if (lane == 0){
    if (g){ s = s*bn_scale(g[o]) + bb[o]; s = fmaxf(s, 0.f); }
    out[wid] = s;
  }
}

extern "C" void kernel_launch(void* const* d_in, const int* in_sizes, int n_in,
                              void* d_out, int out_size, void* d_ws, size_t ws_size,
                              hipStream_t stream){
  const float* x   = (const float*)d_in[0];
  const float* w1  = (const float*)d_in[1];
  const float* w2  = (const float*)d_in[2];
  const float* w3  = (const float*)d_in[3];
  const float* w4  = (const float*)d_in[4];
  const float* w5  = (const float*)d_in[5];
  const float* fw1 = (const float*)d_in[6];
  const float* fw2 = (const float*)d_in[7];
  const float* fw3 = (const float*)d_in[8];
  const float* g1 = (const float*)d_in[9];  const float* b1 = (const float*)d_in[10];
  const float* g2 = (const float*)d_in[11]; const float* b2 = (const float*)d_in[12];
  const float* g3 = (const float*)d_in[13]; const float* b3 = (const float*)d_in[14];
  const float* g4 = (const float*)d_in[15]; const float* b4 = (const float*)d_in[16];
  const float* g5 = (const float*)d_in[17]; const float* b5 = (const float*)d_in[18];
  const float* g6 = (const float*)d_in[19]; const float* b6 = (const float*)d_in[20];
  const float* g7 = (const float*)d_in[21]; const float* b7 = (const float*)d_in[22];

  float* ws = (float*)d_ws;
  size_t off = 0;
  // x1..x3 channel-major; this 4.19M-float region is later reused as xcat_lo
  float* x1  = ws + off; off += (size_t)BATCH*64*NPTS;
  float* x2  = ws + off; off += (size_t)BATCH*64*NPTS;
  float* x3  = ws + off; off += (size_t)BATCH*128*NPTS;
  unsigned short* xcat_lo = (unsigned short*)x1;           // alias: x1..x3 dead before xcat runs
  unsigned short* xcat_hi = (unsigned short*)(ws + off); off += (size_t)BATCH*256*NPTS; // = B*N*512 bf16
  float* x1T = ws + off; off += (size_t)BATCH*64*NPTS;
  float* x2T = ws + off; off += (size_t)BATCH*64*NPTS;
  float* x3T = ws + off; off += (size_t)BATCH*128*NPTS;
  float* x4T = ws + off; off += (size_t)BATCH*256*NPTS;
  float* xT0 = ws + off; off += (size_t)BATCH*3*NPTS;
  float* sq  = ws + off; off += (size_t)BATCH*NPTS;
  int*  idx  = (int*)(ws + off); off += (size_t)BATCH*NPTS*KNN;
  float* out5 = ws + off; off += BATCH*1024;
  float* h6 = ws + off;   off += BATCH*512;
  float* h7 = ws + off;   off += BATCH*256;
  float* wnT1 = ws + off; off += 3*64;
  float* wdT1 = ws + off; off += 3*64;
  unsigned short* wn2 = (unsigned short*)(ws + off); off += 64*64/2;
  unsigned short* wd2 = (unsigned short*)(ws + off); off += 64*64/2;
  unsigned short* wn3 = (unsigned short*)(ws + off); off += 128*64/2;
  unsigned short* wd3 = (unsigned short*)(ws + off); off += 128*64/2;
  unsigned short* wn4 = (unsigned short*)(ws + off); off += 256*128/2;
  unsigned short* wd4 = (unsigned short*)(ws + off); off += 256*128/2;
  unsigned short* w5hi = (unsigned short*)(ws + off); off += 1024*512/2;
  unsigned short* w5lo = (unsigned short*)(ws + off); off += 1024*512/2;

  dim3 gridKNN(NPTS/8, BATCH);
  dim3 gridEC(NPTS/4, BATCH);

  // layer 1 (C=3 -> 64, fp32)
  xt0_kernel<<<64, 256, 0, stream>>>(x, xT0);
  sqnorm_kernel<<<64, 256, 0, stream>>>(x, sq, 3);
  knn_kernel<3><<<gridKNN, 256, 0, stream>>>(x, sq, idx);
  wprep_kernel<<<1, 256, 0, stream>>>(w1, wnT1, wdT1, 64, 3);
  edgeconv1_kernel<<<gridEC, 256, 0, stream>>>(xT0, idx, wnT1, wdT1, g1, b1, x1T);
  transpose2d_kernel<<<dim3(2,64,BATCH), 256, 0, stream>>>(x1T, x1, NPTS, 64);
  // layer 2 (C=64 -> 64, bf16 MFMA)
  sqnorm_kernel<<<64, 256, 0, stream>>>(x1, sq, 64);
  knn_kernel<64><<<gridKNN, 256, 0, stream>>>(x1, sq, idx);
  wprep_bf_kernel<<<16, 256, 0, stream>>>(w2, wn2, wd2, 64, 64);
  edgeconv_mfma<64,64><<<gridEC, 256, 0, stream>>>(x1T, idx, wn2, wd2, g2, b2, x2T);
  transpose2d_kernel<<<dim3(2,64,BATCH), 256, 0, stream>>>(x2T, x2, NPTS, 64);
  // layer 3 (C=64 -> 128, bf16 MFMA)
  sqnorm_kernel<<<64, 256, 0, stream>>>(x2, sq, 64);
  knn_kernel<64><<<gridKNN, 256, 0, stream>>>(x2, sq, idx);
  wprep_bf_kernel<<<32, 256, 0, stream>>>(w3, wn3, wd3, 128, 64);
  edgeconv_mfma<64,128><<<gridEC, 256, 0, stream>>>(x2T, idx, wn3, wd3, g3, b3, x3T);
  transpose2d_kernel<<<dim3(4,64,BATCH), 256, 0, stream>>>(x3T, x3, NPTS, 128);
  // layer 4 (C=128 -> 256, bf16 MFMA)
  sqnorm_kernel<<<64, 256, 0, stream>>>(x3, sq, 128);
  knn_kernel<128><<<gridKNN, 256, 0, stream>>>(x3, sq, idx);
  wprep_bf_kernel<<<128, 256, 0, stream>>>(w4, wn4, wd4, 256, 128);
  edgeconv_mfma<128,256><<<gridEC, 256, 0, stream>>>(x3T, idx, wn4, wd4, g4, b4, x4T);
  // conv5 (split-bf16 MFMA, LDS-staged) + global max over n
  xcat_kernel<<<(BATCH*NPTS*128)/256, 256, 0, stream>>>(x1T, x2T, x3T, x4T, xcat_hi, xcat_lo);
  bfsplit_kernel<<<512, 256, 0, stream>>>(w5, w5hi, w5lo, 1024*512/4);
  zero_kernel<<<32, 256, 0, stream>>>(out5, BATCH*1024);
  conv5_v3<<<dim3(BATCH*NPTS/128, 16), 256, 0, stream>>>(xcat_hi, xcat_lo, w5hi, w5lo, g5, b5, out5);
  // FC head (wave-per-output, coalesced)
  fc_wave_kernel<<<(BATCH*512*64)/256, 256, 0, stream>>>(out5, fw1, g6, b6, h6, 1024, 512);
  fc_wave_kernel<<<(BATCH*256*64)/256, 256, 0, stream>>>(h6, fw2, g7, b7, h7, 512, 256);
  fc_wave_kernel<<<(BATCH*40*64 + 255)/256, 256, 0, stream>>>(h7, fw3, nullptr, nullptr, (float*)d_out, 256, 40);
}

// Round 20
// 849.054 us; speedup vs baseline: 1.2568x; 1.0251x over previous
//
#include <hip/hip_runtime.h>
#include <hip/hip_bf16.h>
#include <math.h>

#define BATCH 8
#define NPTS  2048
#define KNN   20
#define NEG_INF (-3.402823466e38f)

static __device__ __forceinline__ float bn_scale(float g){ return g * rsqrtf(1.0f + 1e-5f); }

// bf16 round-to-nearest-even
static __device__ __forceinline__ unsigned short bf16r(float f){
  unsigned int u = __float_as_uint(f);
  unsigned int r = (u + 0x7fffu + ((u >> 16) & 1u)) >> 16;
  return (unsigned short)r;
}
static __device__ __forceinline__ float bf2f(unsigned short h){
  return __uint_as_float((unsigned int)h << 16);
}
// ordered-int encode/decode for float max via atomicMax(uint)
static __device__ __forceinline__ unsigned int fenc(float f){
  unsigned int u = __float_as_uint(f);
  return (u & 0x80000000u) ? ~u : (u | 0x80000000u);
}
static __device__ __forceinline__ float fdec(unsigned int e){
  return __uint_as_float((e & 0x80000000u) ? (e & 0x7fffffffu) : ~e);
}

using bfrag = __attribute__((ext_vector_type(8))) short;  // 8 bf16 (4 VGPRs)
using f32x4 = __attribute__((ext_vector_type(4))) float;  // 4 fp32 acc
using f32x2 = __attribute__((ext_vector_type(2))) float;  // packed pair -> v_pk_fma_f32

// ---- DPP-based wave argmax (lexicographic value desc, idx asc); winner in lane 63 ----
template<int CTRL>
static __device__ __forceinline__ void dpp_amax(float &bv, int &bi){
  int ov_i = __builtin_amdgcn_update_dpp(__float_as_int(NEG_INF), __float_as_int(bv),
                                         CTRL, 0xf, 0xf, false);
  int oi   = __builtin_amdgcn_update_dpp(0x7fffffff, bi, CTRL, 0xf, 0xf, false);
  float ov = __int_as_float(ov_i);
  if (ov > bv || (ov == bv && oi < bi)){ bv = ov; bi = oi; }
}
static __device__ __forceinline__ int wave_argmax_idx(float bv, int bi){
  dpp_amax<0x111>(bv, bi);   // row_shr:1
  dpp_amax<0x112>(bv, bi);   // row_shr:2
  dpp_amax<0x114>(bv, bi);   // row_shr:4
  dpp_amax<0x118>(bv, bi);   // row_shr:8
  dpp_amax<0x142>(bv, bi);   // row_bcast:15
  dpp_amax<0x143>(bv, bi);   // row_bcast:31
  return __builtin_amdgcn_readlane(bi, 63);
}
// ---- DPP wave sum (identity 0.0 injected); total broadcast from lane 63 ----
template<int CTRL>
static __device__ __forceinline__ float dpp_fadd(float v){
  int ov = __builtin_amdgcn_update_dpp(0, __float_as_int(v), CTRL, 0xf, 0xf, false);
  return v + __int_as_float(ov);
}
static __device__ __forceinline__ float wave_sum(float v){
  v = dpp_fadd<0x111>(v); v = dpp_fadd<0x112>(v);
  v = dpp_fadd<0x114>(v); v = dpp_fadd<0x118>(v);
  v = dpp_fadd<0x142>(v); v = dpp_fadd<0x143>(v);
  return __int_as_float(__builtin_amdgcn_readlane(__float_as_int(v), 63));
}

// ---------------- squared norms per point (reads channel-major [C][N]) ----------------
__global__ void sqnorm_kernel(const float* __restrict__ X, float* __restrict__ sq, int C){
  int i = blockIdx.x*blockDim.x + threadIdx.x;
  if (i >= BATCH*NPTS) return;
  int b = i / NPTS, n = i - b*NPTS;
  const float* xb = X + (size_t)b*C*NPTS + n;
  float s = 0.f;
  for (int c=0;c<C;++c){ float v = xb[(size_t)c*NPTS]; s += v*v; }
  sq[i] = s;
}

// ---------------- kNN v10 (measured best): pk-f32 dist + top-4 queue + DPP argmax ------
template<int C>
__global__ __launch_bounds__(256, 2) void knn_kernel(const float* __restrict__ X,
                                                     const float* __restrict__ sq,
                                                     int* __restrict__ idxout){
  const int b = blockIdx.y;
  const int n0 = blockIdx.x * 8;
  const int t = threadIdx.x;
  __shared__ __align__(16) float dist[4][NPTS];
  __shared__ float ctrs[C][8];
  __shared__ float sqn[8];
  const float* xb = X + (size_t)b*C*NPTS;
  for (int i=t; i<C*8; i+=256){
    int c = i >> 3, p = i & 7;
    ctrs[c][p] = xb[(size_t)c*NPTS + n0 + p];
  }
  if (t < 8) sqn[t] = sq[b*NPTS + n0 + t];
  __syncthreads();

  const int m0 = t * 8;
  f32x2 acc2[8][4];
  #pragma unroll
  for (int i=0;i<8;++i)
    #pragma unroll
    for (int j=0;j<4;++j) acc2[i][j] = (f32x2){0.f, 0.f};
  for (int c=0;c<C;++c){
    const float4 xa = *(const float4*)&xb[(size_t)c*NPTS + m0];
    const float4 xc = *(const float4*)&xb[(size_t)c*NPTS + m0 + 4];
    const f32x2 xm2[4] = {(f32x2){xa.x,xa.y}, (f32x2){xa.z,xa.w},
                          (f32x2){xc.x,xc.y}, (f32x2){xc.z,xc.w}};
    #pragma unroll
    for (int i=0;i<8;++i){
      const float cv = ctrs[c][i];
      const f32x2 cv2 = (f32x2){cv, cv};
      #pragma unroll
      for (int j=0;j<4;++j) acc2[i][j] += cv2*xm2[j];   // v_pk_fma_f32
    }
  }
  {
    const float4 sa = *(const float4*)&sq[b*NPTS + m0];
    const float4 sb = *(const float4*)&sq[b*NPTS + m0 + 4];
    const f32x2 sm2[4] = {(f32x2){sa.x,sa.y}, (f32x2){sa.z,sa.w},
                          (f32x2){sb.x,sb.y}, (f32x2){sb.z,sb.w}};
    #pragma unroll
    for (int i=0;i<8;++i){
      const float si = sqn[i];
      const f32x2 si2 = (f32x2){si, si};
      #pragma unroll
      for (int j=0;j<4;++j) acc2[i][j] = (f32x2){2.f,2.f}*acc2[i][j] - si2 - sm2[j];
    }
  }

  const int wv = t >> 6, lane = t & 63;
  #pragma unroll
  for (int rep=0; rep<2; ++rep){
    #pragma unroll
    for (int i=0;i<4;++i){
      const int r = rep*4 + i;
      *(float4*)&dist[i][m0]   = make_float4(acc2[r][0].x, acc2[r][0].y, acc2[r][1].x, acc2[r][1].y);
      *(float4*)&dist[i][m0+4] = make_float4(acc2[r][2].x, acc2[r][2].y, acc2[r][3].x, acc2[r][3].y);
    }
    __syncthreads();
    // initial scan: per-lane sorted top-4 (value desc, idx asc) in registers
    float s0=NEG_INF,s1=NEG_INF,s2=NEG_INF,s3=NEG_INF;
    int   i0=0x7fffffff,i1=0x7fffffff,i2=0x7fffffff,i3=0x7fffffff;
    #pragma unroll
    for (int j=0;j<32;++j){
      const float v = dist[wv][lane + 64*j];
      const int   m = lane + 64*j;
      const bool b0 = v > s0, b1 = v > s1, b2 = v > s2, b3 = v > s3;  // strict: stable ties
      const float n0 = b0 ? v : s0;            const int q0 = b0 ? m : i0;
      const float n1 = b0 ? s0 : (b1 ? v : s1); const int q1 = b0 ? i0 : (b1 ? m : i1);
      const float n2 = b1 ? s1 : (b2 ? v : s2); const int q2 = b1 ? i1 : (b2 ? m : i2);
      const float n3 = b2 ? s2 : (b3 ? v : s3); const int q3 = b2 ? i2 : (b3 ? m : i3);
      s0=n0;s1=n1;s2=n2;s3=n3; i0=q0;i1=q1;i2=q2;i3=q3;
    }
    int rem = 4;
    int* row = idxout + ((size_t)b*NPTS + n0 + rep*4 + wv)*KNN;
    for (int sel=0; sel<KNN; ++sel){
      const int widx = wave_argmax_idx(s0, i0);   // DPP reduction over queue heads
      if (lane == 0) row[sel] = widx;
      if ((widx & 63) == lane){
        const float lastv = s0; const int lasti = i0;
        s0=s1;i0=i1; s1=s2;i1=i2; s2=s3;i2=i3;
        rem--;
        if (rem == 0){
          float nv = NEG_INF; int ni = 0x7fffffff;
          #pragma unroll
          for (int j=0;j<32;++j){
            const float vv = dist[wv][lane + 64*j];
            const int   mi = lane + 64*j;
            const bool ok = (vv < lastv) || (vv == lastv && mi > lasti);
            if (ok && vv > nv){ nv = vv; ni = mi; }
          }
          s0 = nv; i0 = ni; rem = 1;
        }
      }
    }
    __syncthreads();
  }
}

// ---------------- fp32 weight prep (layer 1 only): wnT[c][o], wdT[c][o] ----------------
__global__ void wprep_kernel(const float* __restrict__ w, float* __restrict__ wnT,
                             float* __restrict__ wdT, int O, int C){
  int i = blockIdx.x*blockDim.x + threadIdx.x;
  if (i >= O*C) return;
  int c = i / O, o = i - c*O;
  float a = w[(size_t)o*2*C + c];
  wnT[(size_t)c*O + o] = a;
  wdT[(size_t)c*O + o] = w[(size_t)o*2*C + C + c] - a;
}

// ---------------- bf16 weight prep (layers 2-4): wn[o][c], wd[o][c] (k contiguous) -----
__global__ void wprep_bf_kernel(const float* __restrict__ w, unsigned short* __restrict__ wn,
                                unsigned short* __restrict__ wd, int O, int C){
  int i = blockIdx.x*blockDim.x + threadIdx.x;
  if (i >= O*C) return;
  int o = i / C, c = i - o*C;
  float a = w[(size_t)o*2*C + c];
  float d = w[(size_t)o*2*C + C + c] - a;
  wn[(size_t)o*C + c] = bf16r(a);
  wd[(size_t)o*C + c] = bf16r(d);
}

// ---------------- split-bf16 weight convert (conv5): hi = bf16(w), lo = bf16(w-hi) ------
__global__ void bfsplit_kernel(const float* __restrict__ in, unsigned short* __restrict__ hi,
                               unsigned short* __restrict__ lo, int nq){
  int i = blockIdx.x*blockDim.x + threadIdx.x;
  if (i >= nq) return;
  float4 v = *(const float4*)&in[(size_t)i*4];
  unsigned short h0=bf16r(v.x), h1=bf16r(v.y), h2=bf16r(v.z), h3=bf16r(v.w);
  unsigned short l0=bf16r(v.x-bf2f(h0)), l1=bf16r(v.y-bf2f(h1)),
                 l2=bf16r(v.z-bf2f(h2)), l3=bf16r(v.w-bf2f(h3));
  *(uint2*)&hi[(size_t)i*4] = make_uint2((unsigned)h0|((unsigned)h1<<16), (unsigned)h2|((unsigned)h3<<16));
  *(uint2*)&lo[(size_t)i*4] = make_uint2((unsigned)l0|((unsigned)l1<<16), (unsigned)l2|((unsigned)l3<<16));
}

// ---------------- xcat: concat x1T..x4T -> split-bf16 [b][n][512] ----------------
__global__ __launch_bounds__(256) void xcat_kernel(const float* __restrict__ x1T,
    const float* __restrict__ x2T, const float* __restrict__ x3T, const float* __restrict__ x4T,
    unsigned short* __restrict__ xhi, unsigned short* __restrict__ xlo){
  int i = blockIdx.x*blockDim.x + threadIdx.x;   // quad index over B*N*128
  if (i >= BATCH*NPTS*128) return;
  int q = i & 127, bn_ = i >> 7;
  int k = q*4;
  const float* src; int kk;
  if (k < 64)      { src = x1T + (size_t)bn_*64;  kk = k; }
  else if (k <128) { src = x2T + (size_t)bn_*64;  kk = k-64; }
  else if (k <256) { src = x3T + (size_t)bn_*128; kk = k-128; }
  else             { src = x4T + (size_t)bn_*256; kk = k-256; }
  float4 v = *(const float4*)&src[kk];
  unsigned short h0=bf16r(v.x), h1=bf16r(v.y), h2=bf16r(v.z), h3=bf16r(v.w);
  unsigned short l0=bf16r(v.x-bf2f(h0)), l1=bf16r(v.y-bf2f(h1)),
                 l2=bf16r(v.z-bf2f(h2)), l3=bf16r(v.w-bf2f(h3));
  *(uint2*)&xhi[(size_t)i*4] = make_uint2((unsigned)h0|((unsigned)h1<<16), (unsigned)h2|((unsigned)h3<<16));
  *(uint2*)&xlo[(size_t)i*4] = make_uint2((unsigned)l0|((unsigned)l1<<16), (unsigned)l2|((unsigned)l3<<16));
}

// ---------------- generic tiled transpose: in[R][Cc] -> out[Cc][R], per z-slice ----------------
__global__ __launch_bounds__(256) void transpose2d_kernel(const float* __restrict__ in,
    float* __restrict__ out, int R, int Cc){
  __shared__ float tile[32][33];
  const size_t boff = (size_t)blockIdx.z * (size_t)R * Cc;
  const int c0 = blockIdx.x*32, r0 = blockIdx.y*32;
  const int tx = threadIdx.x & 31, ty = threadIdx.x >> 5;
  #pragma unroll
  for (int j=0;j<4;++j){
    int r = ty*4 + j;
    tile[r][tx] = in[boff + (size_t)(r0+r)*Cc + c0 + tx];
  }
  __syncthreads();
  #pragma unroll
  for (int j=0;j<4;++j){
    int r = ty*4 + j;
    out[boff + (size_t)(c0+r)*R + r0 + tx] = tile[tx][r];
  }
}

// ---------------- x -> xT0 [N][3] ----------------
__global__ void xt0_kernel(const float* __restrict__ x, float* __restrict__ xT0){
  int i = blockIdx.x*blockDim.x + threadIdx.x;
  if (i >= BATCH*NPTS) return;
  int b = i / NPTS, n = i - b*NPTS;
  const float* xb = x + (size_t)b*3*NPTS;
  float v0 = xb[n], v1 = xb[NPTS + n], v2 = xb[2*NPTS + n];
  float* o = xT0 + ((size_t)b*NPTS + n)*3;
  o[0]=v0; o[1]=v1; o[2]=v2;
}

// ---------------- edge conv layer 1 (C=3, fp32): 4 points per block ----------------
__global__ __launch_bounds__(256) void edgeconv1_kernel(const float* __restrict__ xT0,
    const int* __restrict__ idx, const float* __restrict__ wnT, const float* __restrict__ wdT,
    const float* __restrict__ g, const float* __restrict__ bb, float* __restrict__ outT){
  const int b = blockIdx.y, n0 = blockIdx.x*4, t = threadIdx.x;
  __shared__ float nbr[4][KNN][3];
  __shared__ float ctr[4][3];
  __shared__ int   idxs[4][KNN];
  const float* xb = xT0 + (size_t)b*NPTS*3;
  if (t < 4*KNN) idxs[t/KNN][t%KNN] = idx[((size_t)b*NPTS + n0 + t/KNN)*KNN + (t%KNN)];
  if (t >= 128 && t < 140){ int i = t-128; ctr[i/3][i%3] = xb[(size_t)(n0 + i/3)*3 + i%3]; }
  __syncthreads();
  for (int i=t; i<4*KNN*3; i+=256){
    int p = i/(KNN*3), r = i - p*(KNN*3), k = r/3, c = r - k*3;
    nbr[p][k][c] = xb[(size_t)idxs[p][k]*3 + c];
  }
  __syncthreads();
  const int p = t >> 6, o = t & 63;
  const float wn0 = wnT[o], wn1 = wnT[64+o], wn2 = wnT[128+o];
  const float cst = ctr[p][0]*wdT[o] + ctr[p][1]*wdT[64+o] + ctr[p][2]*wdT[128+o];
  float best = NEG_INF;
  #pragma unroll
  for (int k=0;k<KNN;++k){
    float a = nbr[p][k][0]*wn0 + nbr[p][k][1]*wn1 + nbr[p][k][2]*wn2;
    best = fmaxf(best, a);
  }
  float vv = (best + cst) * bn_scale(g[o]) + bb[o];
  outT[((size_t)b*NPTS + n0 + p)*64 + o] = fmaxf(vv, 0.f);
}

// ---------------- edge conv MFMA (bf16): block = 4 points ----------------
template<int C, int O>
__global__ __launch_bounds__(256) void edgeconv_mfma(const float* __restrict__ xT,
    const int* __restrict__ idx,
    const unsigned short* __restrict__ wn_bf, const unsigned short* __restrict__ wd_bf,
    const float* __restrict__ g, const float* __restrict__ bb, float* __restrict__ outT){
  constexpr int ROWS = 112;        // 7 m-tiles of 16
  constexpr int CP   = C + 8;      // padded row (bf16): 16B-aligned stride, conflict-free b128
  constexpr int KS   = C / 32;     // k-steps per tile
  constexpr int NTW  = O / 64;     // n-tiles per wave (O/16 tiles over 4 waves)
  __shared__ __align__(16) unsigned short A[ROWS][CP];
  __shared__ unsigned int res[4][O];
  __shared__ float cst_s[4][O];
  __shared__ int idxs[4][KNN];
  const int b = blockIdx.y, n0 = blockIdx.x*4, t = threadIdx.x;
  const float* xTb = xT + (size_t)b*NPTS*C;
  if (t < 4*KNN) idxs[t/KNN][t%KNN] = idx[((size_t)b*NPTS + n0 + t/KNN)*KNN + (t%KNN)];
  for (int i=t; i<4*O; i+=256) res[i/O][i & (O-1)] = 0u;   // 0 < fenc(any finite)
  __syncthreads();
  for (int i=t; i<ROWS*(C/4); i+=256){
    int r = i/(C/4), c4 = i - r*(C/4);
    float4 v = make_float4(0.f,0.f,0.f,0.f);
    if (r < 96){
      int p = r/24, kk = r - p*24;
      int src = idxs[p][kk < KNN ? kk : 0];        // pad rows duplicate nbr 0 (max-neutral)
      v = *(const float4*)&xTb[(size_t)src*C + c4*4];
    } else if (r < 100){
      v = *(const float4*)&xTb[(size_t)(n0 + (r-96))*C + c4*4];
    }
    unsigned int lo = (unsigned int)bf16r(v.x) | ((unsigned int)bf16r(v.y) << 16);
    unsigned int hi = (unsigned int)bf16r(v.z) | ((unsigned int)bf16r(v.w) << 16);
    *(uint2*)&A[r][c4*4] = make_uint2(lo, hi);
  }
  __syncthreads();

  const int wv = t >> 6, l = t & 63;
  const int lane15 = l & 15, quad = l >> 4;
  bfrag Bn[NTW][KS];
  #pragma unroll
  for (int nt=0; nt<NTW; ++nt){
    const int col = (wv*NTW + nt)*16 + lane15;
    #pragma unroll
    for (int s=0; s<KS; ++s)
      Bn[nt][s] = *(const bfrag*)&wn_bf[(size_t)col*C + s*32 + quad*8];
  }
  #pragma unroll
  for (int mt=0; mt<7; ++mt){
    bfrag Af[KS];
    #pragma unroll
    for (int s=0; s<KS; ++s)
      Af[s] = *(const bfrag*)&A[mt*16 + lane15][s*32 + quad*8];
    if (mt < 6){
      const int rbase = mt*16 + quad*4;
      const int p = rbase / 24;
      #pragma unroll
      for (int nt=0; nt<NTW; ++nt){
        f32x4 acc = {0.f,0.f,0.f,0.f};
        #pragma unroll
        for (int s=0; s<KS; ++s)
          acc = __builtin_amdgcn_mfma_f32_16x16x32_bf16(Af[s], Bn[nt][s], acc, 0, 0, 0);
        float m = fmaxf(fmaxf(acc[0], acc[1]), fmaxf(acc[2], acc[3]));
        const int col = (wv*NTW + nt)*16 + lane15;
        atomicMax(&res[p][col], fenc(m));
      }
    } else {
      #pragma unroll
      for (int nt=0; nt<NTW; ++nt){
        const int col = (wv*NTW + nt)*16 + lane15;
        f32x4 acc = {0.f,0.f,0.f,0.f};
        #pragma unroll
        for (int s=0; s<KS; ++s){
          bfrag Bd = *(const bfrag*)&wd_bf[(size_t)col*C + s*32 + quad*8];
          acc = __builtin_amdgcn_mfma_f32_16x16x32_bf16(Af[s], Bd, acc, 0, 0, 0);
        }
        if (quad == 0){
          #pragma unroll
          for (int r=0;r<4;++r) cst_s[r][col] = acc[r];
        }
      }
    }
  }
  __syncthreads();
  for (int i=t; i<4*O; i+=256){
    int p = i/O, o = i - p*O;
    float mx = fdec(res[p][o]);
    float vv = (mx + cst_s[p][o]) * bn_scale(g[o]) + bb[o];
    outT[((size_t)b*NPTS + n0 + p)*O + o] = fmaxf(vv, 0.f);
  }
}

// ---------------- conv5 v3: LDS-staged split-bf16 MFMA GEMM + max over n ----------------
__global__ __launch_bounds__(256) void conv5_v3(const unsigned short* __restrict__ xhi,
    const unsigned short* __restrict__ xlo, const unsigned short* __restrict__ whi,
    const unsigned short* __restrict__ wlo, const float* __restrict__ g,
    const float* __restrict__ bb, float* __restrict__ out5){
  __shared__ __align__(16) unsigned short Ah_s[128*32];
  __shared__ __align__(16) unsigned short Al_s[128*32];
  __shared__ __align__(16) unsigned short Bh_s[64*32];
  __shared__ __align__(16) unsigned short Bl_s[64*32];
  const int t = threadIdx.x;
  const int row0 = blockIdx.x*128, o0 = blockIdx.y*64;
  const int b = row0 / NPTS;   // 128 | NPTS, so a block never straddles batches
  const int wv = t >> 6, l = t & 63, lane15 = l & 15, quad = l >> 4;
  const int ar = t >> 2, ac = (t & 3)*8;
  const unsigned short* gAh0 = xhi + (size_t)(row0 + ar)*512 + ac;
  const unsigned short* gAh1 = xhi + (size_t)(row0 + 64 + ar)*512 + ac;
  const unsigned short* gAl0 = xlo + (size_t)(row0 + ar)*512 + ac;
  const unsigned short* gAl1 = xlo + (size_t)(row0 + 64 + ar)*512 + ac;
  const unsigned short* gBh  = whi + (size_t)(o0 + ar)*512 + ac;
  const unsigned short* gBl  = wlo + (size_t)(o0 + ar)*512 + ac;

  uint4 pf0 = *(const uint4*)gAh0;
  uint4 pf1 = *(const uint4*)gAh1;
  uint4 pf2 = *(const uint4*)gAl0;
  uint4 pf3 = *(const uint4*)gAl1;
  uint4 pf4 = *(const uint4*)gBh;
  uint4 pf5 = *(const uint4*)gBl;

  f32x4 acc[2][4];
  #pragma unroll
  for (int mt=0;mt<2;++mt)
    #pragma unroll
    for (int nt=0;nt<4;++nt) acc[mt][nt] = (f32x4){0.f,0.f,0.f,0.f};

  for (int ks=0; ks<16; ++ks){
    *(uint4*)&Ah_s[t*8]        = pf0;
    *(uint4*)&Ah_s[2048 + t*8] = pf1;
    *(uint4*)&Al_s[t*8]        = pf2;
    *(uint4*)&Al_s[2048 + t*8] = pf3;
    *(uint4*)&Bh_s[t*8]        = pf4;
    *(uint4*)&Bl_s[t*8]        = pf5;
    __syncthreads();
    if (ks < 15){
      const int koff = (ks+1)*32;
      pf0 = *(const uint4*)(gAh0 + koff);
      pf1 = *(const uint4*)(gAh1 + koff);
      pf2 = *(const uint4*)(gAl0 + koff);
      pf3 = *(const uint4*)(gAl1 + koff);
      pf4 = *(const uint4*)(gBh  + koff);
      pf5 = *(const uint4*)(gBl  + koff);
    }
    bfrag Afh[2], Afl[2], Bfh[4], Bfl[4];
    #pragma unroll
    for (int mt=0;mt<2;++mt){
      const int m = wv*32 + mt*16 + lane15;
      Afh[mt] = *(const bfrag*)&Ah_s[m*32 + quad*8];
      Afl[mt] = *(const bfrag*)&Al_s[m*32 + quad*8];
    }
    #pragma unroll
    for (int nt=0;nt<4;++nt){
      const int oc = nt*16 + lane15;
      Bfh[nt] = *(const bfrag*)&Bh_s[oc*32 + quad*8];
      Bfl[nt] = *(const bfrag*)&Bl_s[oc*32 + quad*8];
    }
    #pragma unroll
    for (int mt=0;mt<2;++mt)
      #pragma unroll
      for (int nt=0;nt<4;++nt){
        acc[mt][nt] = __builtin_amdgcn_mfma_f32_16x16x32_bf16(Afh[mt], Bfh[nt], acc[mt][nt], 0, 0, 0);
        acc[mt][nt] = __builtin_amdgcn_mfma_f32_16x16x32_bf16(Afl[mt], Bfh[nt], acc[mt][nt], 0, 0, 0);
        acc[mt][nt] = __builtin_amdgcn_mfma_f32_16x16x32_bf16(Afh[mt], Bfl[nt], acc[mt][nt], 0, 0, 0);
      }
    __syncthreads();
  }
  #pragma unroll
  for (int nt=0;nt<4;++nt){
    float m = NEG_INF;
    #pragma unroll
    for (int mt=0;mt<2;++mt)
      #pragma unroll
      for (int r=0;r<4;++r) m = fmaxf(m, acc[mt][nt][r]);
    m = fmaxf(m, __shfl_xor(m, 16, 64));
    m = fmaxf(m, __shfl_xor(m, 32, 64));
    if (quad == 0){
      const int o = o0 + nt*16 + lane15;
      float vv = fmaxf(m * bn_scale(g[o]) + bb[o], 0.f);
      atomicMax((int*)&out5[(size_t)b*1024 + o], __float_as_int(vv));
    }
  }
}

__global__ void zero_kernel(float* __restrict__ p, int nfloats){
  int i = blockIdx.x*blockDim.x + threadIdx.x;
  if (i < nfloats) p[i] = 0.f;
}

// ---------------- FC layers: one wave per (b,o), coalesced lane-strided reads ----------
__global__ __launch_bounds__(256) void fc_wave_kernel(const float* __restrict__ in,
    const float* __restrict__ w, const float* __restrict__ g, const float* __restrict__ bb,
    float* __restrict__ out, int IN, int O){
  const int wid = (blockIdx.x*256 + threadIdx.x) >> 6;
  const int lane = threadIdx.x & 63;
  if (wid >= BATCH*O) return;
  const int b = wid / O, o = wid - b*O;
  const float* inb = in + (size_t)b*IN;
  const float* wo  = w + (size_t)o*IN;
  float s = 0.f;
  for (int c = lane; c < IN; c += 64) s += inb[c]*wo[c];   // coalesced across the wave
  s = wave_sum(s);
  if (lane == 0){
    if (g){ s = s*bn_scale(g[o]) + bb[o]; s = fmaxf(s, 0.f); }
    out[wid] = s;
  }
}

extern "C" void kernel_launch(void* const* d_in, const int* in_sizes, int n_in,
                              void* d_out, int out_size, void* d_ws, size_t ws_size,
                              hipStream_t stream){
  const float* x   = (const float*)d_in[0];
  const float* w1  = (const float*)d_in[1];
  const float* w2  = (const float*)d_in[2];
  const float* w3  = (const float*)d_in[3];
  const float* w4  = (const float*)d_in[4];
  const float* w5  = (const float*)d_in[5];
  const float* fw1 = (const float*)d_in[6];
  const float* fw2 = (const float*)d_in[7];
  const float* fw3 = (const float*)d_in[8];
  const float* g1 = (const float*)d_in[9];  const float* b1 = (const float*)d_in[10];
  const float* g2 = (const float*)d_in[11]; const float* b2 = (const float*)d_in[12];
  const float* g3 = (const float*)d_in[13]; const float* b3 = (const float*)d_in[14];
  const float* g4 = (const float*)d_in[15]; const float* b4 = (const float*)d_in[16];
  const float* g5 = (const float*)d_in[17]; const float* b5 = (const float*)d_in[18];
  const float* g6 = (const float*)d_in[19]; const float* b6 = (const float*)d_in[20];
  const float* g7 = (const float*)d_in[21]; const float* b7 = (const float*)d_in[22];

  float* ws = (float*)d_ws;
  size_t off = 0;
  // x1..x3 channel-major; this 4.19M-float region is later reused as xcat_lo
  float* x1  = ws + off; off += (size_t)BATCH*64*NPTS;
  float* x2  = ws + off; off += (size_t)BATCH*64*NPTS;
  float* x3  = ws + off; off += (size_t)BATCH*128*NPTS;
  unsigned short* xcat_lo = (unsigned short*)x1;           // alias: x1..x3 dead before xcat runs
  unsigned short* xcat_hi = (unsigned short*)(ws + off); off += (size_t)BATCH*256*NPTS; // = B*N*512 bf16
  float* x1T = ws + off; off += (size_t)BATCH*64*NPTS;
  float* x2T = ws + off; off += (size_t)BATCH*64*NPTS;
  float* x3T = ws + off; off += (size_t)BATCH*128*NPTS;
  float* x4T = ws + off; off += (size_t)BATCH*256*NPTS;
  float* xT0 = ws + off; off += (size_t)BATCH*3*NPTS;
  float* sq  = ws + off; off += (size_t)BATCH*NPTS;
  int*  idx  = (int*)(ws + off); off += (size_t)BATCH*NPTS*KNN;
  float* out5 = ws + off; off += BATCH*1024;
  float* h6 = ws + off;   off += BATCH*512;
  float* h7 = ws + off;   off += BATCH*256;
  float* wnT1 = ws + off; off += 3*64;
  float* wdT1 = ws + off; off += 3*64;
  unsigned short* wn2 = (unsigned short*)(ws + off); off += 64*64/2;
  unsigned short* wd2 = (unsigned short*)(ws + off); off += 64*64/2;
  unsigned short* wn3 = (unsigned short*)(ws + off); off += 128*64/2;
  unsigned short* wd3 = (unsigned short*)(ws + off); off += 128*64/2;
  unsigned short* wn4 = (unsigned short*)(ws + off); off += 256*128/2;
  unsigned short* wd4 = (unsigned short*)(ws + off); off += 256*128/2;
  unsigned short* w5hi = (unsigned short*)(ws + off); off += 1024*512/2;
  unsigned short* w5lo = (unsigned short*)(ws + off); off += 1024*512/2;

  dim3 gridKNN(NPTS/8, BATCH);
  dim3 gridEC(NPTS/4, BATCH);

  // layer 1 (C=3 -> 64, fp32)
  xt0_kernel<<<64, 256, 0, stream>>>(x, xT0);
  sqnorm_kernel<<<64, 256, 0, stream>>>(x, sq, 3);
  knn_kernel<3><<<gridKNN, 256, 0, stream>>>(x, sq, idx);
  wprep_kernel<<<1, 256, 0, stream>>>(w1, wnT1, wdT1, 64, 3);
  edgeconv1_kernel<<<gridEC, 256, 0, stream>>>(xT0, idx, wnT1, wdT1, g1, b1, x1T);
  transpose2d_kernel<<<dim3(2,64,BATCH), 256, 0, stream>>>(x1T, x1, NPTS, 64);
  // layer 2 (C=64 -> 64, bf16 MFMA)
  sqnorm_kernel<<<64, 256, 0, stream>>>(x1, sq, 64);
  knn_kernel<64><<<gridKNN, 256, 0, stream>>>(x1, sq, idx);
  wprep_bf_kernel<<<16, 256, 0, stream>>>(w2, wn2, wd2, 64, 64);
  edgeconv_mfma<64,64><<<gridEC, 256, 0, stream>>>(x1T, idx, wn2, wd2, g2, b2, x2T);
  transpose2d_kernel<<<dim3(2,64,BATCH), 256, 0, stream>>>(x2T, x2, NPTS, 64);
  // layer 3 (C=64 -> 128, bf16 MFMA)
  sqnorm_kernel<<<64, 256, 0, stream>>>(x2, sq, 64);
  knn_kernel<64><<<gridKNN, 256, 0, stream>>>(x2, sq, idx);
  wprep_bf_kernel<<<32, 256, 0, stream>>>(w3, wn3, wd3, 128, 64);
  edgeconv_mfma<64,128><<<gridEC, 256, 0, stream>>>(x2T, idx, wn3, wd3, g3, b3, x3T);
  transpose2d_kernel<<<dim3(4,64,BATCH), 256, 0, stream>>>(x3T, x3, NPTS, 128);
  // layer 4 (C=128 -> 256, bf16 MFMA)
  sqnorm_kernel<<<64, 256, 0, stream>>>(x3, sq, 128);
  knn_kernel<128><<<gridKNN, 256, 0, stream>>>(x3, sq, idx);
  wprep_bf_kernel<<<128, 256, 0, stream>>>(w4, wn4, wd4, 256, 128);
  edgeconv_mfma<128,256><<<gridEC, 256, 0, stream>>>(x3T, idx, wn4, wd4, g4, b4, x4T);
  // conv5 (split-bf16 MFMA, LDS-staged) + global max over n
  xcat_kernel<<<(BATCH*NPTS*128)/256, 256, 0, stream>>>(x1T, x2T, x3T, x4T, xcat_hi, xcat_lo);
  bfsplit_kernel<<<512, 256, 0, stream>>>(w5, w5hi, w5lo, 1024*512/4);
  zero_kernel<<<32, 256, 0, stream>>>(out5, BATCH*1024);
  conv5_v3<<<dim3(BATCH*NPTS/128, 16), 256, 0, stream>>>(xcat_hi, xcat_lo, w5hi, w5lo, g5, b5, out5);
  // FC head (wave-per-output, coalesced)
  fc_wave_kernel<<<(BATCH*512*64)/256, 256, 0, stream>>>(out5, fw1, g6, b6, h6, 1024, 512);
  fc_wave_kernel<<<(BATCH*256*64)/256, 256, 0, stream>>>(h6, fw2, g7, b7, h7, 512, 256);
  fc_wave_kernel<<<(BATCH*40*64 + 255)/256, 256, 0, stream>>>(h7, fw3, nullptr, nullptr, (float*)d_out, 256, 40);
}